// Round 18
// baseline (109.444 us; speedup 1.0000x reference)
//
#include <hip/hip_runtime.h>
#include <hip/hip_bf16.h>

#define B_  8
#define C_  512
#define T_  1024
#define NH_ 8
#define HD_ 64

// exp(S) computed as exp2(S*log2e); log2e folded into Wq/bq scale.
#define QSCALE 0.1803368801111243f   // 0.125 * log2(e)

using short8 = __attribute__((ext_vector_type(8))) short;
using f32x4  = __attribute__((ext_vector_type(4))) float;
using f32x16 = __attribute__((ext_vector_type(16))) float;
using us4    = __attribute__((ext_vector_type(4))) unsigned short;

__device__ __forceinline__ unsigned short f2bf(float f) {
    unsigned u = __builtin_bit_cast(unsigned, f);
    u += 0x7fff + ((u >> 16) & 1);
    return (unsigned short)(u >> 16);
}
__device__ __forceinline__ unsigned pack2bf(float lo, float hi) {
    __hip_bfloat162 h = __float22bfloat162_rn(float2{lo, hi});
    unsigned u;
    __builtin_memcpy(&u, &h, 4);
    return u;
}

// async global->LDS, 16B per lane. LDS dest = wave-uniform base + lane*16.
__device__ __forceinline__ void gload_lds16(const ushort* g, ushort* l) {
    __builtin_amdgcn_global_load_lds(
        (const __attribute__((address_space(1))) void*)g,
        (__attribute__((address_space(3))) void*)l, 16, 0, 0);
}

// counted vmcnt wait + scheduling fence (rule 18)
template <int N>
__device__ __forceinline__ void wait_vmcnt() {
    asm volatile("s_waitcnt vmcnt(%0)" ::"n"(N) : "memory");
    __builtin_amdgcn_sched_barrier(0);
}
__device__ __forceinline__ void barrier_raw() {
    __builtin_amdgcn_sched_barrier(0);
    __builtin_amdgcn_s_barrier();
}

// ---------------- K0: fused prep — x transpose + W transposes ----------------
__global__ __launch_bounds__(256) void k_prep(const float* __restrict__ x,
                                              const float* __restrict__ Wq,
                                              const float* __restrict__ Wk,
                                              const float* __restrict__ Wv,
                                              const float* __restrict__ Wo,
                                              ushort* __restrict__ xt,
                                              ushort* __restrict__ Wqkvt,
                                              ushort* __restrict__ Wot) {
    __shared__ float tile[32][33];
    int L = blockIdx.x;
    int tx = threadIdx.x & 31, ty = threadIdx.x >> 5;
    if (L < 4096) {
        int b = L >> 9, rem = L & 511;
        int t0 = (rem & 31) * 32, c0 = (rem >> 5) * 32;
#pragma unroll
        for (int i = 0; i < 4; i++)
            tile[ty + i * 8][tx] = x[((size_t)b * C_ + c0 + ty + i * 8) * T_ + t0 + tx];
        __syncthreads();
#pragma unroll
        for (int i = 0; i < 4; i++)
            xt[((size_t)b * T_ + t0 + ty + i * 8) * C_ + c0 + tx] = f2bf(tile[tx][ty + i * 8]);
    } else {
        int LL = L - 4096;
        int m = LL >> 8, rem = LL & 255;
        int k0 = (rem & 15) * 32, n0 = (rem >> 4) * 32;
        const float* W = (m == 0) ? Wq : (m == 1) ? Wk : (m == 2) ? Wv : Wo;
        ushort* dst = (m < 3) ? (Wqkvt + (size_t)m * C_ * C_) : Wot;
        float scale = (m == 0) ? QSCALE : 1.0f;
#pragma unroll
        for (int i = 0; i < 4; i++)
            tile[ty + i * 8][tx] = W[(size_t)(k0 + ty + i * 8) * C_ + n0 + tx];
        __syncthreads();
#pragma unroll
        for (int i = 0; i < 4; i++)
            dst[(size_t)(n0 + ty + i * 8) * C_ + k0 + tx] = f2bf(tile[tx][ty + i * 8] * scale);
    }
}

// ---------------- GEMM mainloop: C[128x128] = A[128xK] * Bt[128xK]^T ----------------
// R16 structure: double-buffered, counted vmcnt(8), 2 barriers/iter.
__device__ __forceinline__ void gemm_core(const ushort* __restrict__ A,
                                          const ushort* __restrict__ Bt,
                                          int row0, int col0, int tid,
                                          ushort (*As)[8192], ushort (*Bs)[8192],
                                          f32x4 acc[4][4]) {
    f32x4 zero = {0.f, 0.f, 0.f, 0.f};
#pragma unroll
    for (int i = 0; i < 4; i++)
#pragma unroll
        for (int j = 0; j < 4; j++) acc[i][j] = zero;
    int lane = tid & 63, w = tid >> 6;
    int ql = lane & 15, g = lane >> 4;
    int wm = (w >> 1) * 64, wn = (w & 1) * 64;
    int srow = lane >> 3;
    int scol8 = (lane & 7) ^ (srow & 7);

#pragma unroll
    for (int i = 0; i < 4; i++) {
        int c = w * 4 + i;
        int r = c * 8 + srow;
        gload_lds16(A + (size_t)(row0 + r) * C_ + scol8 * 8, As[0] + c * 512);
        gload_lds16(Bt + (size_t)(col0 + r) * C_ + scol8 * 8, Bs[0] + c * 512);
    }

#pragma unroll
    for (int kt = 0; kt < 8; kt++) {
        int cur = kt & 1;
        if (kt < 7) {
            int k0 = (kt + 1) * 64;
#pragma unroll
            for (int i = 0; i < 4; i++) {
                int c = w * 4 + i;
                int r = c * 8 + srow;
                gload_lds16(A + (size_t)(row0 + r) * C_ + k0 + scol8 * 8, As[cur ^ 1] + c * 512);
                gload_lds16(Bt + (size_t)(col0 + r) * C_ + k0 + scol8 * 8, Bs[cur ^ 1] + c * 512);
            }
            wait_vmcnt<8>();
        } else {
            wait_vmcnt<0>();
        }
        barrier_raw();
        const ushort* Ac = As[cur];
        const ushort* Bc = Bs[cur];
        __builtin_amdgcn_s_setprio(1);
#pragma unroll
        for (int s = 0; s < 2; s++) {
            short8 a[4], b[4];
            int cs = ((4 * s + g) ^ (ql & 7)) * 8;
#pragma unroll
            for (int mt = 0; mt < 4; mt++)
                a[mt] = *(const short8*)(Ac + (wm + mt * 16 + ql) * 64 + cs);
#pragma unroll
            for (int nt = 0; nt < 4; nt++)
                b[nt] = *(const short8*)(Bc + (wn + nt * 16 + ql) * 64 + cs);
#pragma unroll
            for (int mt = 0; mt < 4; mt++)
#pragma unroll
                for (int nt = 0; nt < 4; nt++)
                    acc[mt][nt] = __builtin_amdgcn_mfma_f32_16x16x32_bf16(
                        a[mt], b[nt], acc[mt][nt], 0, 0, 0);
        }
        __builtin_amdgcn_s_setprio(0);
        barrier_raw();
    }
}

// ---------------- K1: QKV projection, LDS-bounce epilogue ----------------
__global__ __launch_bounds__(256) void k_qkv(const ushort* __restrict__ xt,
                                             const ushort* __restrict__ Wqkvt,
                                             const float* __restrict__ bq,
                                             const float* __restrict__ bk,
                                             const float* __restrict__ bv,
                                             ushort* __restrict__ Qh,
                                             ushort* __restrict__ Kh,
                                             ushort* __restrict__ Vt) {
    __shared__ __align__(16) ushort As[2][8192];
    __shared__ __align__(16) ushort Bs[2][8192];
    f32x4 acc[4][4];
    int tid = threadIdx.x;
    int L = blockIdx.x;
    int n = L >> 3, xcd = L & 7;
    int row0 = (xcd * 8 + (n & 7)) * 128;
    int col0 = (n >> 3) * 128;
    gemm_core(xt, Wqkvt, row0, col0, tid, As, Bs, acc);
    int lane = tid & 63, w = tid >> 6;
    int ql = lane & 15, g = lane >> 4;
    int wm = (w >> 1) * 64, wn = (w & 1) * 64;
    int which = col0 >> 9;  // 0=Q 1=K 2=V
    const float* bias = (which == 0) ? bq : (which == 1) ? bk : bv;
    float bscale = (which == 0) ? QSCALE : 1.0f;
    ushort* Lt = &As[0][0];  // 32KB bounce tile (gemm LDS dead)

    if (which != 2) {
        ushort* dst = (which == 0) ? Qh : Kh;
#pragma unroll
        for (int mt = 0; mt < 4; mt++)
#pragma unroll
            for (int nt = 0; nt < 4; nt++) {
                int col = wn + nt * 16 + ql;
                float bsv = bias[(col0 + col) & 511] * bscale;
#pragma unroll
                for (int r = 0; r < 4; r++) {
                    int row = wm + mt * 16 + 4 * g + r;
                    int sw = col ^ ((row & 7) << 3);
                    Lt[row * 128 + sw] = f2bf(acc[mt][nt][r] + bsv);
                }
            }
        __syncthreads();
#pragma unroll
        for (int i = 0; i < 8; i++) {
            int task = w * 512 + i * 64 + lane;
            int row = task >> 4, gran = task & 15;
            int sg = gran ^ (row & 7);
            short8 vle = *(const short8*)(Lt + row * 128 + sg * 8);
            int gcol = col0 + gran * 8;
            int hc = gcol & 511, h = hc >> 6, d = hc & 63;
            int grow = row0 + row, b = grow >> 10, t = grow & 1023;
            *(short8*)(dst + ((size_t)(b * NH_ + h) * T_ + t) * HD_ + d) = vle;
        }
    } else {
#pragma unroll
        for (int mt = 0; mt < 4; mt++)
#pragma unroll
            for (int nt = 0; nt < 4; nt++) {
                int col = wn + nt * 16 + ql;
                float bsv = bias[(col0 + col) & 511] * bscale;
                int rowb = wm + mt * 16 + 4 * g;
                int swz = (rowb >> 2) ^ (col & 31);
                us4 pk;
#pragma unroll
                for (int r = 0; r < 4; r++) pk[r] = f2bf(acc[mt][nt][r] + bsv);
                *(us4*)(Lt + col * 128 + swz * 4) = pk;
            }
        __syncthreads();
#pragma unroll
        for (int i = 0; i < 8; i++) {
            int task = w * 512 + i * 64 + lane;
            int colr = task >> 4, gran = task & 15;
            int g4a = (2 * gran) ^ (colr & 31);
            int g4b = (2 * gran + 1) ^ (colr & 31);
            us4 lo = *(const us4*)(Lt + colr * 128 + g4a * 4);
            us4 hi4 = *(const us4*)(Lt + colr * 128 + g4b * 4);
            us4 arr[2] = {lo, hi4};
            short8 vle;
            __builtin_memcpy(&vle, arr, 16);
            int gcol = col0 + colr;
            int hc = gcol & 511, h = hc >> 6, d = hc & 63;
            int grow = row0 + gran * 8, b = grow >> 10, t = grow & 1023;
            *(short8*)(Vt + ((size_t)(b * NH_ + h) * HD_ + d) * T_ + t) = vle;
        }
    }
}

// ---------------- K2: flash attention (R16 structure, lsum in VALU) ----------------
// Change vs R16: l-sum no longer via ones-MFMA (was 4/20 MFMA per tile on the
// critical matrix pipe); accumulate in-lane f32 during exp/pack (VALU, hidden
// under PV's MFMA cluster), finalize via shfl_xor(32) (R8-verified reduction).
__global__ __launch_bounds__(256) void k_attn(const ushort* __restrict__ Qh,
                                              const ushort* __restrict__ Kh,
                                              const ushort* __restrict__ Vt,
                                              ushort* __restrict__ Y) {
    __shared__ __align__(16) ushort KV[8][4096];  // K slots 0-3, V slots 4-7
    int tid = threadIdx.x, lane = tid & 63, w = tid >> 6;
    int hi = lane >> 5, l31 = lane & 31, l7 = lane & 7;
    int bh = blockIdx.x & 63, q0 = (blockIdx.x >> 6) * 128;
    int b = bh >> 3, h = bh & 7;
    int srow = lane >> 3;
    int scol8 = l7 ^ (srow & 7);
    const ushort* Kbase = Kh + (size_t)bh * T_ * HD_;
    const ushort* Vbase = Vt + (size_t)bh * HD_ * T_;
    const ushort* kv = &KV[0][0];

    short8 qa[4];
#pragma unroll
    for (int s = 0; s < 4; s++)
        qa[s] = *(const short8*)(Qh + ((size_t)bh * T_ + q0 + w * 32 + l31) * HD_ +
                                 s * 16 + hi * 8);

    int fofs[4];
#pragma unroll
    for (int s = 0; s < 4; s++) fofs[s] = ((2 * s + hi) ^ l7) * 8;
    int rowlo = l31 * 64;

    f32x16 o0, o1, z16;
#pragma unroll
    for (int i = 0; i < 16; i++) { o0[i] = 0.f; o1[i] = 0.f; z16[i] = 0.f; }
    float lsum = 0.f;

    // parity-banked packed-P from previous tile (compile-time indexed)
    unsigned pk0[2][8], pk1[2][8];

#define PV_BLOCK(P0, P1, VSL)                                                   \
    __builtin_amdgcn_s_setprio(1);                                              \
    _Pragma("unroll")                                                           \
    for (int t4 = 0; t4 < 4; t4++) {                                            \
        const int h2 = t4 & 1;                                                  \
        unsigned c0, c1, c2v, c3v;                                              \
        if (t4 < 2) { c0 = (P0)[4 * h2 + 0]; c2v = (P0)[4 * h2 + 2];            \
                      c1 = (P0)[4 * h2 + 1]; c3v = (P0)[4 * h2 + 3]; }          \
        else        { c0 = (P1)[4 * h2 + 0]; c2v = (P1)[4 * h2 + 2];            \
                      c1 = (P1)[4 * h2 + 1]; c3v = (P1)[4 * h2 + 3]; }          \
        asm("v_permlane32_swap_b32 %0, %1" : "+v"(c0), "+v"(c2v));              \
        asm("v_permlane32_swap_b32 %0, %1" : "+v"(c1), "+v"(c3v));              \
        unsigned au[4] = {c0, c1, c2v, c3v};                                    \
        short8 pa;                                                              \
        __builtin_memcpy(&pa, au, 16);                                          \
        short8 vb0 = *(const short8*)(kv + (4 + (VSL)) * 4096 + rowlo + fofs[t4]);        \
        short8 vb1 = *(const short8*)(kv + (4 + (VSL)) * 4096 + 2048 + rowlo + fofs[t4]); \
        o0 = __builtin_amdgcn_mfma_f32_32x32x16_bf16(pa, vb0, o0, 0, 0, 0);     \
        o1 = __builtin_amdgcn_mfma_f32_32x32x16_bf16(pa, vb1, o1, 0, 0, 0);     \
    }                                                                           \
    __builtin_amdgcn_s_setprio(0);

    // prologue: tiles 0,1 -> slots 0,1
#pragma unroll
    for (int tt = 0; tt < 2; tt++) {
#pragma unroll
        for (int i = 0; i < 2; i++) {
            int c = w * 2 + i;
            int r = c * 8 + srow;
            gload_lds16(Kbase + (size_t)(tt * 64 + r) * HD_ + scol8 * 8,
                        &KV[tt][0] + c * 512);
            gload_lds16(Vbase + (size_t)r * T_ + tt * 64 + scol8 * 8,
                        &KV[4 + tt][0] + c * 512);
        }
    }

#pragma unroll
    for (int t = 0; t < 16; t++) {
        const int sl = t & 3;
        const int par = t & 1;
        if (t < 15) {
            wait_vmcnt<4>();
        } else {
            wait_vmcnt<0>();
        }
        barrier_raw();
        if (t < 14) {
            const int ds = (t + 2) & 3;
            int kv0 = (t + 2) * 64;
#pragma unroll
            for (int i = 0; i < 2; i++) {
                int c = w * 2 + i;
                int r = c * 8 + srow;
                gload_lds16(Kbase + (size_t)(kv0 + r) * HD_ + scol8 * 8,
                            &KV[ds][0] + c * 512);
                gload_lds16(Vbase + (size_t)r * T_ + kv0 + scol8 * 8,
                            &KV[4 + ds][0] + c * 512);
            }
        }

        f32x16 sT0, sT1;
        __builtin_amdgcn_s_setprio(1);
        {
            short8 ka0 = *(const short8*)(kv + sl * 4096 + rowlo + fofs[0]);
            short8 ka1 = *(const short8*)(kv + sl * 4096 + 2048 + rowlo + fofs[0]);
            sT0 = __builtin_amdgcn_mfma_f32_32x32x16_bf16(ka0, qa[0], z16, 0, 0, 0);
            sT1 = __builtin_amdgcn_mfma_f32_32x32x16_bf16(ka1, qa[0], z16, 0, 0, 0);
        }
#pragma unroll
        for (int s = 1; s < 4; s++) {
            short8 ka0 = *(const short8*)(kv + sl * 4096 + rowlo + fofs[s]);
            short8 ka1 = *(const short8*)(kv + sl * 4096 + 2048 + rowlo + fofs[s]);
            sT0 = __builtin_amdgcn_mfma_f32_32x32x16_bf16(ka0, qa[s], sT0, 0, 0, 0);
            sT1 = __builtin_amdgcn_mfma_f32_32x32x16_bf16(ka1, qa[s], sT1, 0, 0, 0);
        }
        __builtin_amdgcn_s_setprio(0);

        if (t == 1 || t == 3 || t == 5 || t == 7 || t == 9 || t == 11 || t == 13 || t == 15) {
            PV_BLOCK(pk0[0], pk1[0], (t - 1) & 3)
        } else if (t > 0) {
            PV_BLOCK(pk0[1], pk1[1], (t - 1) & 3)
        }

        // exp/pack(t) into parity bank par; in-lane lsum accumulation (VALU)
#pragma unroll
        for (int i = 0; i < 8; i++) {
            float a0 = __builtin_amdgcn_exp2f(sT0[2 * i]);
            float a1 = __builtin_amdgcn_exp2f(sT0[2 * i + 1]);
            float b0v = __builtin_amdgcn_exp2f(sT1[2 * i]);
            float b1v = __builtin_amdgcn_exp2f(sT1[2 * i + 1]);
            pk0[par][i] = pack2bf(a0, a1);
            pk1[par][i] = pack2bf(b0v, b1v);
            lsum += (a0 + a1) + (b0v + b1v);
        }
    }

    PV_BLOCK(pk0[1], pk1[1], 3)
#undef PV_BLOCK

    // full denominator for q=l31: add complementary hi-half's k-subset
    float linv = 1.0f / (lsum + __shfl_xor(lsum, 32));
#pragma unroll
    for (int r = 0; r < 16; r++) {
        int qr = (r & 3) + 8 * (r >> 2) + 4 * hi;
        float li = __shfl(linv, qr);
        int trow = q0 + w * 32 + qr;
        size_t base = ((size_t)b * T_ + trow) * C_ + h * HD_;
        Y[base + l31] = f2bf(o0[r] * li);
        Y[base + 32 + l31] = f2bf(o1[r] * li);
    }
}

// ---------------- K3: O projection + bias + residual, out (B,C,T) fp32 ----------------
__global__ __launch_bounds__(256) void k_oproj(const ushort* __restrict__ Y,
                                               const ushort* __restrict__ Wot,
                                               const float* __restrict__ bo,
                                               const float* __restrict__ x,
                                               float* __restrict__ out) {
    __shared__ __align__(16) ushort As[2][8192];
    __shared__ __align__(16) ushort Bs[2][8192];
    f32x4 acc[4][4];
    int tid = threadIdx.x;
    int L = blockIdx.x;
    int n = L >> 3, xcd = L & 7;
    int row0 = (xcd * 8 + (n & 7)) * 128;
    int col0 = (n >> 3) * 128;
    gemm_core(Y, Wot, row0, col0, tid, As, Bs, acc);
    int lane = tid & 63, w = tid >> 6;
    int wm = (w >> 1) * 64, wn = (w & 1) * 64;
#pragma unroll
    for (int mt = 0; mt < 4; mt++) {
        int grow0 = row0 + wm + mt * 16 + ((lane >> 4) << 2);
        int b = grow0 >> 10, t = grow0 & 1023;
#pragma unroll
        for (int nt = 0; nt < 4; nt++) {
            int c = col0 + wn + nt * 16 + (lane & 15);
            float bsv = bo[c];
            size_t off = ((size_t)b * C_ + c) * T_ + t;
            float4 xv = *(const float4*)(x + off);
            float4 ov;
            ov.x = acc[mt][nt][0] + xv.x + bsv;
            ov.y = acc[mt][nt][1] + xv.y + bsv;
            ov.z = acc[mt][nt][2] + xv.z + bsv;
            ov.w = acc[mt][nt][3] + xv.w + bsv;
            *(float4*)(out + off) = ov;
        }
    }
}

extern "C" void kernel_launch(void* const* d_in, const int* in_sizes, int n_in,
                              void* d_out, int out_size, void* d_ws, size_t ws_size,
                              hipStream_t stream) {
    const float* x  = (const float*)d_in[0];
    const float* Wq = (const float*)d_in[1];
    const float* bq = (const float*)d_in[2];
    const float* Wk = (const float*)d_in[3];
    const float* bk = (const float*)d_in[4];
    const float* Wv = (const float*)d_in[5];
    const float* bv = (const float*)d_in[6];
    const float* Wo = (const float*)d_in[7];
    const float* bo = (const float*)d_in[8];
    float* out = (float*)d_out;

    char* ws = (char*)d_ws;
    ushort* xt    = (ushort*)(ws + 0);          // 8 MB; reused as Y after K1
    ushort* Wqkvt = (ushort*)(ws + 8388608);
    ushort* Wot   = (ushort*)(ws + 9961472);
    ushort* Qh    = (ushort*)(ws + 10485760);
    ushort* Kh    = (ushort*)(ws + 18874368);
    ushort* Vt    = (ushort*)(ws + 27262976);
    ushort* Yw    = xt;

    k_prep<<<dim3(5120), 256, 0, stream>>>(x, Wq, Wk, Wv, Wo, xt, Wqkvt, Wot);
    k_qkv<<<dim3(768), 256, 0, stream>>>(xt, Wqkvt, bq, bk, bv, Qh, Kh, Vt);
    k_attn<<<dim3(512), 256, 0, stream>>>(Qh, Kh, Vt, Yw);
    k_oproj<<<dim3(256), 256, 0, stream>>>(Yw, Wot, bo, x, out);
}

// Round 19
// 72.510 us; speedup vs baseline: 1.5094x; 1.5094x over previous
//
#include <hip/hip_runtime.h>
#include <hip/hip_bf16.h>

#define B_  8
#define C_  512
#define T_  1024
#define NH_ 8
#define HD_ 64

// exp(S) computed as exp2(S*log2e); log2e folded into Wq/bq scale.
#define QSCALE 0.1803368801111243f   // 0.125 * log2(e)

using short8 = __attribute__((ext_vector_type(8))) short;
using f32x4  = __attribute__((ext_vector_type(4))) float;
using f32x16 = __attribute__((ext_vector_type(16))) float;
using us4    = __attribute__((ext_vector_type(4))) unsigned short;

__device__ __forceinline__ unsigned short f2bf(float f) {
    unsigned u = __builtin_bit_cast(unsigned, f);
    u += 0x7fff + ((u >> 16) & 1);
    return (unsigned short)(u >> 16);
}
__device__ __forceinline__ unsigned pack2bf(float lo, float hi) {
    __hip_bfloat162 h = __float22bfloat162_rn(float2{lo, hi});
    unsigned u;
    __builtin_memcpy(&u, &h, 4);
    return u;
}

// async global->LDS, 16B per lane. LDS dest = wave-uniform base + lane*16.
__device__ __forceinline__ void gload_lds16(const ushort* g, ushort* l) {
    __builtin_amdgcn_global_load_lds(
        (const __attribute__((address_space(1))) void*)g,
        (__attribute__((address_space(3))) void*)l, 16, 0, 0);
}

// counted vmcnt wait + scheduling fence (rule 18)
template <int N>
__device__ __forceinline__ void wait_vmcnt() {
    asm volatile("s_waitcnt vmcnt(%0)" ::"n"(N) : "memory");
    __builtin_amdgcn_sched_barrier(0);
}
__device__ __forceinline__ void barrier_raw() {
    __builtin_amdgcn_sched_barrier(0);
    __builtin_amdgcn_s_barrier();
}

// ---------------- K0: fused prep — x transpose + W transposes ----------------
__global__ __launch_bounds__(256) void k_prep(const float* __restrict__ x,
                                              const float* __restrict__ Wq,
                                              const float* __restrict__ Wk,
                                              const float* __restrict__ Wv,
                                              const float* __restrict__ Wo,
                                              ushort* __restrict__ xt,
                                              ushort* __restrict__ Wqkvt,
                                              ushort* __restrict__ Wot) {
    __shared__ float tile[32][33];
    int L = blockIdx.x;
    int tx = threadIdx.x & 31, ty = threadIdx.x >> 5;
    if (L < 4096) {
        int b = L >> 9, rem = L & 511;
        int t0 = (rem & 31) * 32, c0 = (rem >> 5) * 32;
#pragma unroll
        for (int i = 0; i < 4; i++)
            tile[ty + i * 8][tx] = x[((size_t)b * C_ + c0 + ty + i * 8) * T_ + t0 + tx];
        __syncthreads();
#pragma unroll
        for (int i = 0; i < 4; i++)
            xt[((size_t)b * T_ + t0 + ty + i * 8) * C_ + c0 + tx] = f2bf(tile[tx][ty + i * 8]);
    } else {
        int LL = L - 4096;
        int m = LL >> 8, rem = LL & 255;
        int k0 = (rem & 15) * 32, n0 = (rem >> 4) * 32;
        const float* W = (m == 0) ? Wq : (m == 1) ? Wk : (m == 2) ? Wv : Wo;
        ushort* dst = (m < 3) ? (Wqkvt + (size_t)m * C_ * C_) : Wot;
        float scale = (m == 0) ? QSCALE : 1.0f;
#pragma unroll
        for (int i = 0; i < 4; i++)
            tile[ty + i * 8][tx] = W[(size_t)(k0 + ty + i * 8) * C_ + n0 + tx];
        __syncthreads();
#pragma unroll
        for (int i = 0; i < 4; i++)
            dst[(size_t)(n0 + ty + i * 8) * C_ + k0 + tx] = f2bf(tile[tx][ty + i * 8] * scale);
    }
}

// ---------------- GEMM mainloop: C[128x128] = A[128xK] * Bt[128xK]^T ----------------
__device__ __forceinline__ void gemm_core(const ushort* __restrict__ A,
                                          const ushort* __restrict__ Bt,
                                          int row0, int col0, int tid,
                                          ushort (*As)[8192], ushort (*Bs)[8192],
                                          f32x4 acc[4][4]) {
    f32x4 zero = {0.f, 0.f, 0.f, 0.f};
#pragma unroll
    for (int i = 0; i < 4; i++)
#pragma unroll
        for (int j = 0; j < 4; j++) acc[i][j] = zero;
    int lane = tid & 63, w = tid >> 6;
    int ql = lane & 15, g = lane >> 4;
    int wm = (w >> 1) * 64, wn = (w & 1) * 64;
    int srow = lane >> 3;
    int scol8 = (lane & 7) ^ (srow & 7);

#pragma unroll
    for (int i = 0; i < 4; i++) {
        int c = w * 4 + i;
        int r = c * 8 + srow;
        gload_lds16(A + (size_t)(row0 + r) * C_ + scol8 * 8, As[0] + c * 512);
        gload_lds16(Bt + (size_t)(col0 + r) * C_ + scol8 * 8, Bs[0] + c * 512);
    }

#pragma unroll
    for (int kt = 0; kt < 8; kt++) {
        int cur = kt & 1;
        if (kt < 7) {
            int k0 = (kt + 1) * 64;
#pragma unroll
            for (int i = 0; i < 4; i++) {
                int c = w * 4 + i;
                int r = c * 8 + srow;
                gload_lds16(A + (size_t)(row0 + r) * C_ + k0 + scol8 * 8, As[cur ^ 1] + c * 512);
                gload_lds16(Bt + (size_t)(col0 + r) * C_ + k0 + scol8 * 8, Bs[cur ^ 1] + c * 512);
            }
            wait_vmcnt<8>();
        } else {
            wait_vmcnt<0>();
        }
        barrier_raw();
        const ushort* Ac = As[cur];
        const ushort* Bc = Bs[cur];
        __builtin_amdgcn_s_setprio(1);
#pragma unroll
        for (int s = 0; s < 2; s++) {
            short8 a[4], b[4];
            int cs = ((4 * s + g) ^ (ql & 7)) * 8;
#pragma unroll
            for (int mt = 0; mt < 4; mt++)
                a[mt] = *(const short8*)(Ac + (wm + mt * 16 + ql) * 64 + cs);
#pragma unroll
            for (int nt = 0; nt < 4; nt++)
                b[nt] = *(const short8*)(Bc + (wn + nt * 16 + ql) * 64 + cs);
#pragma unroll
            for (int mt = 0; mt < 4; mt++)
#pragma unroll
                for (int nt = 0; nt < 4; nt++)
                    acc[mt][nt] = __builtin_amdgcn_mfma_f32_16x16x32_bf16(
                        a[mt], b[nt], acc[mt][nt], 0, 0, 0);
        }
        __builtin_amdgcn_s_setprio(0);
        barrier_raw();
    }
}

// ---------------- K1: QKV projection, LDS-bounce epilogue ----------------
__global__ __launch_bounds__(256) void k_qkv(const ushort* __restrict__ xt,
                                             const ushort* __restrict__ Wqkvt,
                                             const float* __restrict__ bq,
                                             const float* __restrict__ bk,
                                             const float* __restrict__ bv,
                                             ushort* __restrict__ Qh,
                                             ushort* __restrict__ Kh,
                                             ushort* __restrict__ Vt) {
    __shared__ __align__(16) ushort As[2][8192];
    __shared__ __align__(16) ushort Bs[2][8192];
    f32x4 acc[4][4];
    int tid = threadIdx.x;
    int L = blockIdx.x;
    int n = L >> 3, xcd = L & 7;
    int row0 = (xcd * 8 + (n & 7)) * 128;
    int col0 = (n >> 3) * 128;
    gemm_core(xt, Wqkvt, row0, col0, tid, As, Bs, acc);
    int lane = tid & 63, w = tid >> 6;
    int ql = lane & 15, g = lane >> 4;
    int wm = (w >> 1) * 64, wn = (w & 1) * 64;
    int which = col0 >> 9;  // 0=Q 1=K 2=V
    const float* bias = (which == 0) ? bq : (which == 1) ? bk : bv;
    float bscale = (which == 0) ? QSCALE : 1.0f;
    ushort* Lt = &As[0][0];  // 32KB bounce tile (gemm LDS dead)

    if (which != 2) {
        ushort* dst = (which == 0) ? Qh : Kh;
#pragma unroll
        for (int mt = 0; mt < 4; mt++)
#pragma unroll
            for (int nt = 0; nt < 4; nt++) {
                int col = wn + nt * 16 + ql;
                float bsv = bias[(col0 + col) & 511] * bscale;
#pragma unroll
                for (int r = 0; r < 4; r++) {
                    int row = wm + mt * 16 + 4 * g + r;
                    int sw = col ^ ((row & 7) << 3);
                    Lt[row * 128 + sw] = f2bf(acc[mt][nt][r] + bsv);
                }
            }
        __syncthreads();
#pragma unroll
        for (int i = 0; i < 8; i++) {
            int task = w * 512 + i * 64 + lane;
            int row = task >> 4, gran = task & 15;
            int sg = gran ^ (row & 7);
            short8 vle = *(const short8*)(Lt + row * 128 + sg * 8);
            int gcol = col0 + gran * 8;
            int hc = gcol & 511, h = hc >> 6, d = hc & 63;
            int grow = row0 + row, b = grow >> 10, t = grow & 1023;
            *(short8*)(dst + ((size_t)(b * NH_ + h) * T_ + t) * HD_ + d) = vle;
        }
    } else {
#pragma unroll
        for (int mt = 0; mt < 4; mt++)
#pragma unroll
            for (int nt = 0; nt < 4; nt++) {
                int col = wn + nt * 16 + ql;
                float bsv = bias[(col0 + col) & 511] * bscale;
                int rowb = wm + mt * 16 + 4 * g;
                int swz = (rowb >> 2) ^ (col & 31);
                us4 pk;
#pragma unroll
                for (int r = 0; r < 4; r++) pk[r] = f2bf(acc[mt][nt][r] + bsv);
                *(us4*)(Lt + col * 128 + swz * 4) = pk;
            }
        __syncthreads();
#pragma unroll
        for (int i = 0; i < 8; i++) {
            int task = w * 512 + i * 64 + lane;
            int colr = task >> 4, gran = task & 15;
            int g4a = (2 * gran) ^ (colr & 31);
            int g4b = (2 * gran + 1) ^ (colr & 31);
            us4 lo = *(const us4*)(Lt + colr * 128 + g4a * 4);
            us4 hi4 = *(const us4*)(Lt + colr * 128 + g4b * 4);
            us4 arr[2] = {lo, hi4};
            short8 vle;
            __builtin_memcpy(&vle, arr, 16);
            int gcol = col0 + colr;
            int hc = gcol & 511, h = hc >> 6, d = hc & 63;
            int grow = row0 + gran * 8, b = grow >> 10, t = grow & 1023;
            *(short8*)(Vt + ((size_t)(b * NH_ + h) * HD_ + d) * T_ + t) = vle;
        }
    }
}

// ---------------- K2: flash attention, 32x32 MFMA, in-register P ----------------
// R13 base (QBLK=128, 4 waves, 4-slot pipeline, single barrier) +
// T15 double-pipeline: PV(t-1) issued right after QK(t) so its MFMAs overlap
// exp/pack(t) VALU/trans work. Prefetch AFTER the barrier (read distance t-1;
// (t+2)-(t-1)=3 < 4 slots -> race-free). ones-MFMA l-sum (o5) kept: it is the
// REGISTER-CHEAPEST l-sum (R18's VALU lsum spilled at 256 VGPR).
__global__ __launch_bounds__(256) void k_attn(const ushort* __restrict__ Qh,
                                              const ushort* __restrict__ Kh,
                                              const ushort* __restrict__ Vt,
                                              ushort* __restrict__ Y) {
    __shared__ __align__(16) ushort KV[8][4096];  // K slots 0-3, V slots 4-7
    int tid = threadIdx.x, lane = tid & 63, w = tid >> 6;
    int hi = lane >> 5, l31 = lane & 31, l7 = lane & 7;
    int bh = blockIdx.x & 63, q0 = (blockIdx.x >> 6) * 128;
    int b = bh >> 3, h = bh & 7;
    int srow = lane >> 3;
    int scol8 = l7 ^ (srow & 7);
    const ushort* Kbase = Kh + (size_t)bh * T_ * HD_;
    const ushort* Vbase = Vt + (size_t)bh * HD_ * T_;
    const ushort* kv = &KV[0][0];

    short8 qa[4];
#pragma unroll
    for (int s = 0; s < 4; s++)
        qa[s] = *(const short8*)(Qh + ((size_t)bh * T_ + q0 + w * 32 + l31) * HD_ +
                                 s * 16 + hi * 8);

    int fofs[4];
#pragma unroll
    for (int s = 0; s < 4; s++) fofs[s] = ((2 * s + hi) ^ l7) * 8;
    int rowlo = l31 * 64;

    short8 ones;
    {
        short ov = (l31 == 0) ? (short)0x3F80 : (short)0;
#pragma unroll
        for (int j = 0; j < 8; j++) ones[j] = ov;
    }

    f32x16 o0, o1, o5, z16;
#pragma unroll
    for (int i = 0; i < 16; i++) { o0[i] = 0.f; o1[i] = 0.f; o5[i] = 0.f; z16[i] = 0.f; }

    // parity-banked packed-P from previous tile (compile-time indexed)
    unsigned pk0[2][8], pk1[2][8];

#define PV_BLOCK(P0, P1, VSL)                                                   \
    __builtin_amdgcn_s_setprio(1);                                              \
    _Pragma("unroll")                                                           \
    for (int t4 = 0; t4 < 4; t4++) {                                            \
        const int h2 = t4 & 1;                                                  \
        unsigned c0, c1, c2v, c3v;                                              \
        if (t4 < 2) { c0 = (P0)[4 * h2 + 0]; c2v = (P0)[4 * h2 + 2];            \
                      c1 = (P0)[4 * h2 + 1]; c3v = (P0)[4 * h2 + 3]; }          \
        else        { c0 = (P1)[4 * h2 + 0]; c2v = (P1)[4 * h2 + 2];            \
                      c1 = (P1)[4 * h2 + 1]; c3v = (P1)[4 * h2 + 3]; }          \
        asm("v_permlane32_swap_b32 %0, %1" : "+v"(c0), "+v"(c2v));              \
        asm("v_permlane32_swap_b32 %0, %1" : "+v"(c1), "+v"(c3v));              \
        unsigned au[4] = {c0, c1, c2v, c3v};                                    \
        short8 pa;                                                              \
        __builtin_memcpy(&pa, au, 16);                                          \
        short8 vb0 = *(const short8*)(kv + (4 + (VSL)) * 4096 + rowlo + fofs[t4]);        \
        short8 vb1 = *(const short8*)(kv + (4 + (VSL)) * 4096 + 2048 + rowlo + fofs[t4]); \
        o0 = __builtin_amdgcn_mfma_f32_32x32x16_bf16(pa, vb0, o0, 0, 0, 0);     \
        o1 = __builtin_amdgcn_mfma_f32_32x32x16_bf16(pa, vb1, o1, 0, 0, 0);     \
        o5 = __builtin_amdgcn_mfma_f32_32x32x16_bf16(pa, ones, o5, 0, 0, 0);    \
    }                                                                           \
    __builtin_amdgcn_s_setprio(0);

    // prologue: tiles 0,1 -> slots 0,1
#pragma unroll
    for (int tt = 0; tt < 2; tt++) {
#pragma unroll
        for (int i = 0; i < 2; i++) {
            int c = w * 2 + i;
            int r = c * 8 + srow;
            gload_lds16(Kbase + (size_t)(tt * 64 + r) * HD_ + scol8 * 8,
                        &KV[tt][0] + c * 512);
            gload_lds16(Vbase + (size_t)r * T_ + tt * 64 + scol8 * 8,
                        &KV[4 + tt][0] + c * 512);
        }
    }

#pragma unroll
    for (int t = 0; t < 16; t++) {
        const int sl = t & 3;
        const int par = t & 1;
        if (t < 15) {
            wait_vmcnt<4>();
        } else {
            wait_vmcnt<0>();
        }
        barrier_raw();
        if (t < 14) {
            const int ds = (t + 2) & 3;
            int kv0 = (t + 2) * 64;
#pragma unroll
            for (int i = 0; i < 2; i++) {
                int c = w * 2 + i;
                int r = c * 8 + srow;
                gload_lds16(Kbase + (size_t)(kv0 + r) * HD_ + scol8 * 8,
                            &KV[ds][0] + c * 512);
                gload_lds16(Vbase + (size_t)r * T_ + kv0 + scol8 * 8,
                            &KV[4 + ds][0] + c * 512);
            }
        }

        f32x16 sT0, sT1;
        __builtin_amdgcn_s_setprio(1);
        {
            short8 ka0 = *(const short8*)(kv + sl * 4096 + rowlo + fofs[0]);
            short8 ka1 = *(const short8*)(kv + sl * 4096 + 2048 + rowlo + fofs[0]);
            sT0 = __builtin_amdgcn_mfma_f32_32x32x16_bf16(ka0, qa[0], z16, 0, 0, 0);
            sT1 = __builtin_amdgcn_mfma_f32_32x32x16_bf16(ka1, qa[0], z16, 0, 0, 0);
        }
#pragma unroll
        for (int s = 1; s < 4; s++) {
            short8 ka0 = *(const short8*)(kv + sl * 4096 + rowlo + fofs[s]);
            short8 ka1 = *(const short8*)(kv + sl * 4096 + 2048 + rowlo + fofs[s]);
            sT0 = __builtin_amdgcn_mfma_f32_32x32x16_bf16(ka0, qa[s], sT0, 0, 0, 0);
            sT1 = __builtin_amdgcn_mfma_f32_32x32x16_bf16(ka1, qa[s], sT1, 0, 0, 0);
        }
        __builtin_amdgcn_s_setprio(0);

        if (t == 1 || t == 3 || t == 5 || t == 7 || t == 9 || t == 11 || t == 13 || t == 15) {
            PV_BLOCK(pk0[0], pk1[0], (t - 1) & 3)
        } else if (t > 0) {
            PV_BLOCK(pk0[1], pk1[1], (t - 1) & 3)
        }

#pragma unroll
        for (int i = 0; i < 8; i++) {
            pk0[par][i] = pack2bf(__builtin_amdgcn_exp2f(sT0[2 * i]),
                                  __builtin_amdgcn_exp2f(sT0[2 * i + 1]));
            pk1[par][i] = pack2bf(__builtin_amdgcn_exp2f(sT1[2 * i]),
                                  __builtin_amdgcn_exp2f(sT1[2 * i + 1]));
        }
    }

    PV_BLOCK(pk0[1], pk1[1], 3)
#undef PV_BLOCK

#pragma unroll
    for (int r = 0; r < 16; r++) {
        float li = 1.0f / __shfl(o5[r], hi * 32);
        int qr = (r & 3) + 8 * (r >> 2) + 4 * hi;
        int trow = q0 + w * 32 + qr;
        size_t base = ((size_t)b * T_ + trow) * C_ + h * HD_;
        Y[base + l31] = f2bf(o0[r] * li);
        Y[base + 32 + l31] = f2bf(o1[r] * li);
    }
}

// ---------------- K3: O projection + bias + residual, out (B,C,T) fp32 ----------------
__global__ __launch_bounds__(256) void k_oproj(const ushort* __restrict__ Y,
                                               const ushort* __restrict__ Wot,
                                               const float* __restrict__ bo,
                                               const float* __restrict__ x,
                                               float* __restrict__ out) {
    __shared__ __align__(16) ushort As[2][8192];
    __shared__ __align__(16) ushort Bs[2][8192];
    f32x4 acc[4][4];
    int tid = threadIdx.x;
    int L = blockIdx.x;
    int n = L >> 3, xcd = L & 7;
    int row0 = (xcd * 8 + (n & 7)) * 128;
    int col0 = (n >> 3) * 128;
    gemm_core(Y, Wot, row0, col0, tid, As, Bs, acc);
    int lane = tid & 63, w = tid >> 6;
    int wm = (w >> 1) * 64, wn = (w & 1) * 64;
#pragma unroll
    for (int mt = 0; mt < 4; mt++) {
        int grow0 = row0 + wm + mt * 16 + ((lane >> 4) << 2);
        int b = grow0 >> 10, t = grow0 & 1023;
#pragma unroll
        for (int nt = 0; nt < 4; nt++) {
            int c = col0 + wn + nt * 16 + (lane & 15);
            float bsv = bo[c];
            size_t off = ((size_t)b * C_ + c) * T_ + t;
            float4 xv = *(const float4*)(x + off);
            float4 ov;
            ov.x = acc[mt][nt][0] + xv.x + bsv;
            ov.y = acc[mt][nt][1] + xv.y + bsv;
            ov.z = acc[mt][nt][2] + xv.z + bsv;
            ov.w = acc[mt][nt][3] + xv.w + bsv;
            *(float4*)(out + off) = ov;
        }
    }
}

extern "C" void kernel_launch(void* const* d_in, const int* in_sizes, int n_in,
                              void* d_out, int out_size, void* d_ws, size_t ws_size,
                              hipStream_t stream) {
    const float* x  = (const float*)d_in[0];
    const float* Wq = (const float*)d_in[1];
    const float* bq = (const float*)d_in[2];
    const float* Wk = (const float*)d_in[3];
    const float* bk = (const float*)d_in[4];
    const float* Wv = (const float*)d_in[5];
    const float* bv = (const float*)d_in[6];
    const float* Wo = (const float*)d_in[7];
    const float* bo = (const float*)d_in[8];
    float* out = (float*)d_out;

    char* ws = (char*)d_ws;
    ushort* xt    = (ushort*)(ws + 0);          // 8 MB; reused as Y after K1
    ushort* Wqkvt = (ushort*)(ws + 8388608);
    ushort* Wot   = (ushort*)(ws + 9961472);
    ushort* Qh    = (ushort*)(ws + 10485760);
    ushort* Kh    = (ushort*)(ws + 18874368);
    ushort* Vt    = (ushort*)(ws + 27262976);
    ushort* Yw    = xt;

    k_prep<<<dim3(5120), 256, 0, stream>>>(x, Wq, Wk, Wv, Wo, xt, Wqkvt, Wot);
    k_qkv<<<dim3(768), 256, 0, stream>>>(xt, Wqkvt, bq, bk, bv, Qh, Kh, Vt);
    k_attn<<<dim3(512), 256, 0, stream>>>(Qh, Kh, Vt, Yw);
    k_oproj<<<dim3(256), 256, 0, stream>>>(Yw, Wot, bo, x, out);
}

// Round 20
// 70.811 us; speedup vs baseline: 1.5456x; 1.0240x over previous
//
#include <hip/hip_runtime.h>
#include <hip/hip_bf16.h>

#define B_  8
#define C_  512
#define T_  1024
#define NH_ 8
#define HD_ 64

// exp(S) computed as exp2(S*log2e); log2e folded into Wq/bq scale.
#define QSCALE 0.1803368801111243f   // 0.125 * log2(e)

using short8 = __attribute__((ext_vector_type(8))) short;
using f32x4  = __attribute__((ext_vector_type(4))) float;
using f32x16 = __attribute__((ext_vector_type(16))) float;
using us4    = __attribute__((ext_vector_type(4))) unsigned short;

__device__ __forceinline__ unsigned short f2bf(float f) {
    unsigned u = __builtin_bit_cast(unsigned, f);
    u += 0x7fff + ((u >> 16) & 1);
    return (unsigned short)(u >> 16);
}
__device__ __forceinline__ unsigned pack2bf(float lo, float hi) {
    __hip_bfloat162 h = __float22bfloat162_rn(float2{lo, hi});
    unsigned u;
    __builtin_memcpy(&u, &h, 4);
    return u;
}

// async global->LDS, 16B per lane. LDS dest = wave-uniform base + lane*16.
__device__ __forceinline__ void gload_lds16(const ushort* g, ushort* l) {
    __builtin_amdgcn_global_load_lds(
        (const __attribute__((address_space(1))) void*)g,
        (__attribute__((address_space(3))) void*)l, 16, 0, 0);
}

// counted vmcnt wait + scheduling fence (rule 18)
template <int N>
__device__ __forceinline__ void wait_vmcnt() {
    asm volatile("s_waitcnt vmcnt(%0)" ::"n"(N) : "memory");
    __builtin_amdgcn_sched_barrier(0);
}
__device__ __forceinline__ void barrier_raw() {
    __builtin_amdgcn_sched_barrier(0);
    __builtin_amdgcn_s_barrier();
}

// ---------------- K0: fused prep — x transpose + W transposes ----------------
__global__ __launch_bounds__(256) void k_prep(const float* __restrict__ x,
                                              const float* __restrict__ Wq,
                                              const float* __restrict__ Wk,
                                              const float* __restrict__ Wv,
                                              const float* __restrict__ Wo,
                                              ushort* __restrict__ xt,
                                              ushort* __restrict__ Wqkvt,
                                              ushort* __restrict__ Wot) {
    __shared__ float tile[32][33];
    int L = blockIdx.x;
    int tx = threadIdx.x & 31, ty = threadIdx.x >> 5;
    if (L < 4096) {
        int b = L >> 9, rem = L & 511;
        int t0 = (rem & 31) * 32, c0 = (rem >> 5) * 32;
#pragma unroll
        for (int i = 0; i < 4; i++)
            tile[ty + i * 8][tx] = x[((size_t)b * C_ + c0 + ty + i * 8) * T_ + t0 + tx];
        __syncthreads();
#pragma unroll
        for (int i = 0; i < 4; i++)
            xt[((size_t)b * T_ + t0 + ty + i * 8) * C_ + c0 + tx] = f2bf(tile[tx][ty + i * 8]);
    } else {
        int LL = L - 4096;
        int m = LL >> 8, rem = LL & 255;
        int k0 = (rem & 15) * 32, n0 = (rem >> 4) * 32;
        const float* W = (m == 0) ? Wq : (m == 1) ? Wk : (m == 2) ? Wv : Wo;
        ushort* dst = (m < 3) ? (Wqkvt + (size_t)m * C_ * C_) : Wot;
        float scale = (m == 0) ? QSCALE : 1.0f;
#pragma unroll
        for (int i = 0; i < 4; i++)
            tile[ty + i * 8][tx] = W[(size_t)(k0 + ty + i * 8) * C_ + n0 + tx];
        __syncthreads();
#pragma unroll
        for (int i = 0; i < 4; i++)
            dst[(size_t)(n0 + ty + i * 8) * C_ + k0 + tx] = f2bf(tile[tx][ty + i * 8] * scale);
    }
}

// ---------------- GEMM mainloop: C[128x128] = A[128xK] * Bt[128xK]^T ----------------
__device__ __forceinline__ void gemm_core(const ushort* __restrict__ A,
                                          const ushort* __restrict__ Bt,
                                          int row0, int col0, int tid,
                                          ushort (*As)[8192], ushort (*Bs)[8192],
                                          f32x4 acc[4][4]) {
    f32x4 zero = {0.f, 0.f, 0.f, 0.f};
#pragma unroll
    for (int i = 0; i < 4; i++)
#pragma unroll
        for (int j = 0; j < 4; j++) acc[i][j] = zero;
    int lane = tid & 63, w = tid >> 6;
    int ql = lane & 15, g = lane >> 4;
    int wm = (w >> 1) * 64, wn = (w & 1) * 64;
    int srow = lane >> 3;
    int scol8 = (lane & 7) ^ (srow & 7);

#pragma unroll
    for (int i = 0; i < 4; i++) {
        int c = w * 4 + i;
        int r = c * 8 + srow;
        gload_lds16(A + (size_t)(row0 + r) * C_ + scol8 * 8, As[0] + c * 512);
        gload_lds16(Bt + (size_t)(col0 + r) * C_ + scol8 * 8, Bs[0] + c * 512);
    }

#pragma unroll
    for (int kt = 0; kt < 8; kt++) {
        int cur = kt & 1;
        if (kt < 7) {
            int k0 = (kt + 1) * 64;
#pragma unroll
            for (int i = 0; i < 4; i++) {
                int c = w * 4 + i;
                int r = c * 8 + srow;
                gload_lds16(A + (size_t)(row0 + r) * C_ + k0 + scol8 * 8, As[cur ^ 1] + c * 512);
                gload_lds16(Bt + (size_t)(col0 + r) * C_ + k0 + scol8 * 8, Bs[cur ^ 1] + c * 512);
            }
            wait_vmcnt<8>();
        } else {
            wait_vmcnt<0>();
        }
        barrier_raw();
        const ushort* Ac = As[cur];
        const ushort* Bc = Bs[cur];
        __builtin_amdgcn_s_setprio(1);
#pragma unroll
        for (int s = 0; s < 2; s++) {
            short8 a[4], b[4];
            int cs = ((4 * s + g) ^ (ql & 7)) * 8;
#pragma unroll
            for (int mt = 0; mt < 4; mt++)
                a[mt] = *(const short8*)(Ac + (wm + mt * 16 + ql) * 64 + cs);
#pragma unroll
            for (int nt = 0; nt < 4; nt++)
                b[nt] = *(const short8*)(Bc + (wn + nt * 16 + ql) * 64 + cs);
#pragma unroll
            for (int mt = 0; mt < 4; mt++)
#pragma unroll
                for (int nt = 0; nt < 4; nt++)
                    acc[mt][nt] = __builtin_amdgcn_mfma_f32_16x16x32_bf16(
                        a[mt], b[nt], acc[mt][nt], 0, 0, 0);
        }
        __builtin_amdgcn_s_setprio(0);
        barrier_raw();
    }
}

// ---------------- K1: QKV projection, LDS-bounce epilogue ----------------
__global__ __launch_bounds__(256) void k_qkv(const ushort* __restrict__ xt,
                                             const ushort* __restrict__ Wqkvt,
                                             const float* __restrict__ bq,
                                             const float* __restrict__ bk,
                                             const float* __restrict__ bv,
                                             ushort* __restrict__ Qh,
                                             ushort* __restrict__ Kh,
                                             ushort* __restrict__ Vt) {
    __shared__ __align__(16) ushort As[2][8192];
    __shared__ __align__(16) ushort Bs[2][8192];
    f32x4 acc[4][4];
    int tid = threadIdx.x;
    int L = blockIdx.x;
    int n = L >> 3, xcd = L & 7;
    int row0 = (xcd * 8 + (n & 7)) * 128;
    int col0 = (n >> 3) * 128;
    gemm_core(xt, Wqkvt, row0, col0, tid, As, Bs, acc);
    int lane = tid & 63, w = tid >> 6;
    int ql = lane & 15, g = lane >> 4;
    int wm = (w >> 1) * 64, wn = (w & 1) * 64;
    int which = col0 >> 9;  // 0=Q 1=K 2=V
    const float* bias = (which == 0) ? bq : (which == 1) ? bk : bv;
    float bscale = (which == 0) ? QSCALE : 1.0f;
    ushort* Lt = &As[0][0];  // 32KB bounce tile (gemm LDS dead)

    if (which != 2) {
        ushort* dst = (which == 0) ? Qh : Kh;
#pragma unroll
        for (int mt = 0; mt < 4; mt++)
#pragma unroll
            for (int nt = 0; nt < 4; nt++) {
                int col = wn + nt * 16 + ql;
                float bsv = bias[(col0 + col) & 511] * bscale;
#pragma unroll
                for (int r = 0; r < 4; r++) {
                    int row = wm + mt * 16 + 4 * g + r;
                    int sw = col ^ ((row & 7) << 3);
                    Lt[row * 128 + sw] = f2bf(acc[mt][nt][r] + bsv);
                }
            }
        __syncthreads();
#pragma unroll
        for (int i = 0; i < 8; i++) {
            int task = w * 512 + i * 64 + lane;
            int row = task >> 4, gran = task & 15;
            int sg = gran ^ (row & 7);
            short8 vle = *(const short8*)(Lt + row * 128 + sg * 8);
            int gcol = col0 + gran * 8;
            int hc = gcol & 511, h = hc >> 6, d = hc & 63;
            int grow = row0 + row, b = grow >> 10, t = grow & 1023;
            *(short8*)(dst + ((size_t)(b * NH_ + h) * T_ + t) * HD_ + d) = vle;
        }
    } else {
#pragma unroll
        for (int mt = 0; mt < 4; mt++)
#pragma unroll
            for (int nt = 0; nt < 4; nt++) {
                int col = wn + nt * 16 + ql;
                float bsv = bias[(col0 + col) & 511] * bscale;
                int rowb = wm + mt * 16 + 4 * g;
                int swz = (rowb >> 2) ^ (col & 31);
                us4 pk;
#pragma unroll
                for (int r = 0; r < 4; r++) pk[r] = f2bf(acc[mt][nt][r] + bsv);
                *(us4*)(Lt + col * 128 + swz * 4) = pk;
            }
        __syncthreads();
#pragma unroll
        for (int i = 0; i < 8; i++) {
            int task = w * 512 + i * 64 + lane;
            int colr = task >> 4, gran = task & 15;
            int g4a = (2 * gran) ^ (colr & 31);
            int g4b = (2 * gran + 1) ^ (colr & 31);
            us4 lo = *(const us4*)(Lt + colr * 128 + g4a * 4);
            us4 hi4 = *(const us4*)(Lt + colr * 128 + g4b * 4);
            us4 arr[2] = {lo, hi4};
            short8 vle;
            __builtin_memcpy(&vle, arr, 16);
            int gcol = col0 + colr;
            int hc = gcol & 511, h = hc >> 6, d = hc & 63;
            int grow = row0 + gran * 8, b = grow >> 10, t = grow & 1023;
            *(short8*)(Vt + ((size_t)(b * NH_ + h) * HD_ + d) * T_ + t) = vle;
        }
    }
}

// ---------------- K2: flash attention (R16/R19 verified structure) ----------------
__global__ __launch_bounds__(256) void k_attn(const ushort* __restrict__ Qh,
                                              const ushort* __restrict__ Kh,
                                              const ushort* __restrict__ Vt,
                                              ushort* __restrict__ Y) {
    __shared__ __align__(16) ushort KV[8][4096];  // K slots 0-3, V slots 4-7
    int tid = threadIdx.x, lane = tid & 63, w = tid >> 6;
    int hi = lane >> 5, l31 = lane & 31, l7 = lane & 7;
    int bh = blockIdx.x & 63, q0 = (blockIdx.x >> 6) * 128;
    int b = bh >> 3, h = bh & 7;
    int srow = lane >> 3;
    int scol8 = l7 ^ (srow & 7);
    const ushort* Kbase = Kh + (size_t)bh * T_ * HD_;
    const ushort* Vbase = Vt + (size_t)bh * HD_ * T_;
    const ushort* kv = &KV[0][0];

    short8 qa[4];
#pragma unroll
    for (int s = 0; s < 4; s++)
        qa[s] = *(const short8*)(Qh + ((size_t)bh * T_ + q0 + w * 32 + l31) * HD_ +
                                 s * 16 + hi * 8);

    int fofs[4];
#pragma unroll
    for (int s = 0; s < 4; s++) fofs[s] = ((2 * s + hi) ^ l7) * 8;
    int rowlo = l31 * 64;

    short8 ones;
    {
        short ov = (l31 == 0) ? (short)0x3F80 : (short)0;
#pragma unroll
        for (int j = 0; j < 8; j++) ones[j] = ov;
    }

    f32x16 o0, o1, o5, z16;
#pragma unroll
    for (int i = 0; i < 16; i++) { o0[i] = 0.f; o1[i] = 0.f; o5[i] = 0.f; z16[i] = 0.f; }

    // parity-banked packed-P from previous tile (compile-time indexed)
    unsigned pk0[2][8], pk1[2][8];

#define PV_BLOCK(P0, P1, VSL)                                                   \
    __builtin_amdgcn_s_setprio(1);                                              \
    _Pragma("unroll")                                                           \
    for (int t4 = 0; t4 < 4; t4++) {                                            \
        const int h2 = t4 & 1;                                                  \
        unsigned c0, c1, c2v, c3v;                                              \
        if (t4 < 2) { c0 = (P0)[4 * h2 + 0]; c2v = (P0)[4 * h2 + 2];            \
                      c1 = (P0)[4 * h2 + 1]; c3v = (P0)[4 * h2 + 3]; }          \
        else        { c0 = (P1)[4 * h2 + 0]; c2v = (P1)[4 * h2 + 2];            \
                      c1 = (P1)[4 * h2 + 1]; c3v = (P1)[4 * h2 + 3]; }          \
        asm("v_permlane32_swap_b32 %0, %1" : "+v"(c0), "+v"(c2v));              \
        asm("v_permlane32_swap_b32 %0, %1" : "+v"(c1), "+v"(c3v));              \
        unsigned au[4] = {c0, c1, c2v, c3v};                                    \
        short8 pa;                                                              \
        __builtin_memcpy(&pa, au, 16);                                          \
        short8 vb0 = *(const short8*)(kv + (4 + (VSL)) * 4096 + rowlo + fofs[t4]);        \
        short8 vb1 = *(const short8*)(kv + (4 + (VSL)) * 4096 + 2048 + rowlo + fofs[t4]); \
        o0 = __builtin_amdgcn_mfma_f32_32x32x16_bf16(pa, vb0, o0, 0, 0, 0);     \
        o1 = __builtin_amdgcn_mfma_f32_32x32x16_bf16(pa, vb1, o1, 0, 0, 0);     \
        o5 = __builtin_amdgcn_mfma_f32_32x32x16_bf16(pa, ones, o5, 0, 0, 0);    \
    }                                                                           \
    __builtin_amdgcn_s_setprio(0);

    // prologue: tiles 0,1 -> slots 0,1
#pragma unroll
    for (int tt = 0; tt < 2; tt++) {
#pragma unroll
        for (int i = 0; i < 2; i++) {
            int c = w * 2 + i;
            int r = c * 8 + srow;
            gload_lds16(Kbase + (size_t)(tt * 64 + r) * HD_ + scol8 * 8,
                        &KV[tt][0] + c * 512);
            gload_lds16(Vbase + (size_t)r * T_ + tt * 64 + scol8 * 8,
                        &KV[4 + tt][0] + c * 512);
        }
    }

#pragma unroll
    for (int t = 0; t < 16; t++) {
        const int sl = t & 3;
        const int par = t & 1;
        if (t < 15) {
            wait_vmcnt<4>();
        } else {
            wait_vmcnt<0>();
        }
        barrier_raw();
        if (t < 14) {
            const int ds = (t + 2) & 3;
            int kv0 = (t + 2) * 64;
#pragma unroll
            for (int i = 0; i < 2; i++) {
                int c = w * 2 + i;
                int r = c * 8 + srow;
                gload_lds16(Kbase + (size_t)(kv0 + r) * HD_ + scol8 * 8,
                            &KV[ds][0] + c * 512);
                gload_lds16(Vbase + (size_t)r * T_ + kv0 + scol8 * 8,
                            &KV[4 + ds][0] + c * 512);
            }
        }

        f32x16 sT0, sT1;
        __builtin_amdgcn_s_setprio(1);
        {
            short8 ka0 = *(const short8*)(kv + sl * 4096 + rowlo + fofs[0]);
            short8 ka1 = *(const short8*)(kv + sl * 4096 + 2048 + rowlo + fofs[0]);
            sT0 = __builtin_amdgcn_mfma_f32_32x32x16_bf16(ka0, qa[0], z16, 0, 0, 0);
            sT1 = __builtin_amdgcn_mfma_f32_32x32x16_bf16(ka1, qa[0], z16, 0, 0, 0);
        }
#pragma unroll
        for (int s = 1; s < 4; s++) {
            short8 ka0 = *(const short8*)(kv + sl * 4096 + rowlo + fofs[s]);
            short8 ka1 = *(const short8*)(kv + sl * 4096 + 2048 + rowlo + fofs[s]);
            sT0 = __builtin_amdgcn_mfma_f32_32x32x16_bf16(ka0, qa[s], sT0, 0, 0, 0);
            sT1 = __builtin_amdgcn_mfma_f32_32x32x16_bf16(ka1, qa[s], sT1, 0, 0, 0);
        }
        __builtin_amdgcn_s_setprio(0);

        if (t == 1 || t == 3 || t == 5 || t == 7 || t == 9 || t == 11 || t == 13 || t == 15) {
            PV_BLOCK(pk0[0], pk1[0], (t - 1) & 3)
        } else if (t > 0) {
            PV_BLOCK(pk0[1], pk1[1], (t - 1) & 3)
        }

#pragma unroll
        for (int i = 0; i < 8; i++) {
            pk0[par][i] = pack2bf(__builtin_amdgcn_exp2f(sT0[2 * i]),
                                  __builtin_amdgcn_exp2f(sT0[2 * i + 1]));
            pk1[par][i] = pack2bf(__builtin_amdgcn_exp2f(sT1[2 * i]),
                                  __builtin_amdgcn_exp2f(sT1[2 * i + 1]));
        }
    }

    PV_BLOCK(pk0[1], pk1[1], 3)
#undef PV_BLOCK

#pragma unroll
    for (int r = 0; r < 16; r++) {
        float li = 1.0f / __shfl(o5[r], hi * 32);
        int qr = (r & 3) + 8 * (r >> 2) + 4 * hi;
        int trow = q0 + w * 32 + qr;
        size_t base = ((size_t)b * T_ + trow) * C_ + h * HD_;
        Y[base + l31] = f2bf(o0[r] * li);
        Y[base + 32 + l31] = f2bf(o1[r] * li);
    }
}

// ---------------- K3: O projection, 128x64 tiles (2 blocks/CU resident) ----------------
// Dedicated core: A-tile 128x64 (16 chunks), B-tile 64x64 (8 chunks); 6 loads
// per wave per K-step, counted vmcnt(6). LDS 48KB -> grid 512 = 2 blocks/CU.
__global__ __launch_bounds__(256) void k_oproj(const ushort* __restrict__ Y,
                                               const ushort* __restrict__ Wot,
                                               const float* __restrict__ bo,
                                               const float* __restrict__ x,
                                               float* __restrict__ out) {
    __shared__ __align__(16) ushort As[2][8192];
    __shared__ __align__(16) ushort Bs[2][4096];
    f32x4 acc[4][2];
    int tid = threadIdx.x;
    int L = blockIdx.x;                    // 512 blocks
    int n = L >> 3, xcd = L & 7;           // n in [0,64)
    int row0 = (xcd * 8 + (n & 7)) * 128;  // 64 row-blocks
    int col0 = (n >> 3) * 64;              // 8 col-blocks

    f32x4 zero = {0.f, 0.f, 0.f, 0.f};
#pragma unroll
    for (int i = 0; i < 4; i++)
#pragma unroll
        for (int j = 0; j < 2; j++) acc[i][j] = zero;
    int lane = tid & 63, w = tid >> 6;
    int ql = lane & 15, g = lane >> 4;
    int wm = (w >> 1) * 64, wn = (w & 1) * 32;
    int srow = lane >> 3;
    int scol8 = (lane & 7) ^ (srow & 7);

    // prologue: K-tile 0 (A: 4 chunks/wave, B: 2 chunks/wave = 6 loads)
#pragma unroll
    for (int i = 0; i < 4; i++) {
        int c = w * 4 + i;
        int r = c * 8 + srow;
        gload_lds16(Y + (size_t)(row0 + r) * C_ + scol8 * 8, As[0] + c * 512);
    }
#pragma unroll
    for (int i = 0; i < 2; i++) {
        int c = w * 2 + i;
        int r = c * 8 + srow;
        gload_lds16(Wot + (size_t)(col0 + r) * C_ + scol8 * 8, Bs[0] + c * 512);
    }

#pragma unroll
    for (int kt = 0; kt < 8; kt++) {
        int cur = kt & 1;
        if (kt < 7) {
            int k0 = (kt + 1) * 64;
#pragma unroll
            for (int i = 0; i < 4; i++) {
                int c = w * 4 + i;
                int r = c * 8 + srow;
                gload_lds16(Y + (size_t)(row0 + r) * C_ + k0 + scol8 * 8,
                            As[cur ^ 1] + c * 512);
            }
#pragma unroll
            for (int i = 0; i < 2; i++) {
                int c = w * 2 + i;
                int r = c * 8 + srow;
                gload_lds16(Wot + (size_t)(col0 + r) * C_ + k0 + scol8 * 8,
                            Bs[cur ^ 1] + c * 512);
            }
            wait_vmcnt<6>();
        } else {
            wait_vmcnt<0>();
        }
        barrier_raw();
        const ushort* Ac = As[cur];
        const ushort* Bc = Bs[cur];
        __builtin_amdgcn_s_setprio(1);
#pragma unroll
        for (int s = 0; s < 2; s++) {
            short8 a[4], b[2];
            int cs = ((4 * s + g) ^ (ql & 7)) * 8;
#pragma unroll
            for (int mt = 0; mt < 4; mt++)
                a[mt] = *(const short8*)(Ac + (wm + mt * 16 + ql) * 64 + cs);
#pragma unroll
            for (int nt = 0; nt < 2; nt++)
                b[nt] = *(const short8*)(Bc + (wn + nt * 16 + ql) * 64 + cs);
#pragma unroll
            for (int mt = 0; mt < 4; mt++)
#pragma unroll
                for (int nt = 0; nt < 2; nt++)
                    acc[mt][nt] = __builtin_amdgcn_mfma_f32_16x16x32_bf16(
                        a[mt], b[nt], acc[mt][nt], 0, 0, 0);
        }
        __builtin_amdgcn_s_setprio(0);
        barrier_raw();
    }

#pragma unroll
    for (int mt = 0; mt < 4; mt++) {
        int grow0 = row0 + wm + mt * 16 + (g << 2);
        int b = grow0 >> 10, t = grow0 & 1023;
#pragma unroll
        for (int nt = 0; nt < 2; nt++) {
            int c = col0 + wn + nt * 16 + ql;
            float bsv = bo[c];
            size_t off = ((size_t)b * C_ + c) * T_ + t;
            float4 xv = *(const float4*)(x + off);
            float4 ov;
            ov.x = acc[mt][nt][0] + xv.x + bsv;
            ov.y = acc[mt][nt][1] + xv.y + bsv;
            ov.z = acc[mt][nt][2] + xv.z + bsv;
            ov.w = acc[mt][nt][3] + xv.w + bsv;
            *(float4*)(out + off) = ov;
        }
    }
}

extern "C" void kernel_launch(void* const* d_in, const int* in_sizes, int n_in,
                              void* d_out, int out_size, void* d_ws, size_t ws_size,
                              hipStream_t stream) {
    const float* x  = (const float*)d_in[0];
    const float* Wq = (const float*)d_in[1];
    const float* bq = (const float*)d_in[2];
    const float* Wk = (const float*)d_in[3];
    const float* bk = (const float*)d_in[4];
    const float* Wv = (const float*)d_in[5];
    const float* bv = (const float*)d_in[6];
    const float* Wo = (const float*)d_in[7];
    const float* bo = (const float*)d_in[8];
    float* out = (float*)d_out;

    char* ws = (char*)d_ws;
    ushort* xt    = (ushort*)(ws + 0);          // 8 MB; reused as Y after K1
    ushort* Wqkvt = (ushort*)(ws + 8388608);
    ushort* Wot   = (ushort*)(ws + 9961472);
    ushort* Qh    = (ushort*)(ws + 10485760);
    ushort* Kh    = (ushort*)(ws + 18874368);
    ushort* Vt    = (ushort*)(ws + 27262976);
    ushort* Yw    = xt;

    k_prep<<<dim3(5120), 256, 0, stream>>>(x, Wq, Wk, Wv, Wo, xt, Wqkvt, Wot);
    k_qkv<<<dim3(768), 256, 0, stream>>>(xt, Wqkvt, bq, bk, bv, Qh, Kh, Vt);
    k_attn<<<dim3(512), 256, 0, stream>>>(Qh, Kh, Vt, Yw);
    k_oproj<<<dim3(512), 256, 0, stream>>>(Yw, Wot, bo, x, out);
}

// Round 21
// 69.994 us; speedup vs baseline: 1.5636x; 1.0117x over previous
//
#include <hip/hip_runtime.h>
#include <hip/hip_bf16.h>

#define B_  8
#define C_  512
#define T_  1024
#define NH_ 8
#define HD_ 64

// exp(S) computed as exp2(S*log2e); log2e folded into Wq/bq scale.
#define QSCALE 0.1803368801111243f   // 0.125 * log2(e)

using short8 = __attribute__((ext_vector_type(8))) short;
using f32x4  = __attribute__((ext_vector_type(4))) float;
using f32x16 = __attribute__((ext_vector_type(16))) float;
using us4    = __attribute__((ext_vector_type(4))) unsigned short;

__device__ __forceinline__ unsigned short f2bf(float f) {
    unsigned u = __builtin_bit_cast(unsigned, f);
    u += 0x7fff + ((u >> 16) & 1);
    return (unsigned short)(u >> 16);
}
__device__ __forceinline__ unsigned pack2bf(float lo, float hi) {
    __hip_bfloat162 h = __float22bfloat162_rn(float2{lo, hi});
    unsigned u;
    __builtin_memcpy(&u, &h, 4);
    return u;
}

// async global->LDS, 16B per lane. LDS dest = wave-uniform base + lane*16.
__device__ __forceinline__ void gload_lds16(const ushort* g, ushort* l) {
    __builtin_amdgcn_global_load_lds(
        (const __attribute__((address_space(1))) void*)g,
        (__attribute__((address_space(3))) void*)l, 16, 0, 0);
}

// counted vmcnt wait + scheduling fence (rule 18)
template <int N>
__device__ __forceinline__ void wait_vmcnt() {
    asm volatile("s_waitcnt vmcnt(%0)" ::"n"(N) : "memory");
    __builtin_amdgcn_sched_barrier(0);
}
__device__ __forceinline__ void barrier_raw() {
    __builtin_amdgcn_sched_barrier(0);
    __builtin_amdgcn_s_barrier();
}

// ---------------- K0: fused prep — x transpose + W transposes ----------------
__global__ __launch_bounds__(256) void k_prep(const float* __restrict__ x,
                                              const float* __restrict__ Wq,
                                              const float* __restrict__ Wk,
                                              const float* __restrict__ Wv,
                                              const float* __restrict__ Wo,
                                              ushort* __restrict__ xt,
                                              ushort* __restrict__ Wqkvt,
                                              ushort* __restrict__ Wot) {
    __shared__ float tile[32][33];
    int L = blockIdx.x;
    int tx = threadIdx.x & 31, ty = threadIdx.x >> 5;
    if (L < 4096) {
        int b = L >> 9, rem = L & 511;
        int t0 = (rem & 31) * 32, c0 = (rem >> 5) * 32;
#pragma unroll
        for (int i = 0; i < 4; i++)
            tile[ty + i * 8][tx] = x[((size_t)b * C_ + c0 + ty + i * 8) * T_ + t0 + tx];
        __syncthreads();
#pragma unroll
        for (int i = 0; i < 4; i++)
            xt[((size_t)b * T_ + t0 + ty + i * 8) * C_ + c0 + tx] = f2bf(tile[tx][ty + i * 8]);
    } else {
        int LL = L - 4096;
        int m = LL >> 8, rem = LL & 255;
        int k0 = (rem & 15) * 32, n0 = (rem >> 4) * 32;
        const float* W = (m == 0) ? Wq : (m == 1) ? Wk : (m == 2) ? Wv : Wo;
        ushort* dst = (m < 3) ? (Wqkvt + (size_t)m * C_ * C_) : Wot;
        float scale = (m == 0) ? QSCALE : 1.0f;
#pragma unroll
        for (int i = 0; i < 4; i++)
            tile[ty + i * 8][tx] = W[(size_t)(k0 + ty + i * 8) * C_ + n0 + tx];
        __syncthreads();
#pragma unroll
        for (int i = 0; i < 4; i++)
            dst[(size_t)(n0 + ty + i * 8) * C_ + k0 + tx] = f2bf(tile[tx][ty + i * 8] * scale);
    }
}

// ---------------- shared 128x64-tile GEMM core ----------------
// A-tile 128x64 (16 chunks), B-tile 64x64 (8 chunks); 6 loads/wave/K-step,
// counted vmcnt(6), double-buffered, 2 barriers/iter. LDS 48KB -> 3 blocks/CU.
__device__ __forceinline__ void gemm_core64(const ushort* __restrict__ A,
                                            const ushort* __restrict__ Bt,
                                            int row0, int col0, int tid,
                                            ushort (*As)[8192], ushort (*Bs)[4096],
                                            f32x4 acc[4][2]) {
    f32x4 zero = {0.f, 0.f, 0.f, 0.f};
#pragma unroll
    for (int i = 0; i < 4; i++)
#pragma unroll
        for (int j = 0; j < 2; j++) acc[i][j] = zero;
    int lane = tid & 63, w = tid >> 6;
    int ql = lane & 15, g = lane >> 4;
    int wm = (w >> 1) * 64, wn = (w & 1) * 32;
    int srow = lane >> 3;
    int scol8 = (lane & 7) ^ (srow & 7);

#pragma unroll
    for (int i = 0; i < 4; i++) {
        int c = w * 4 + i;
        int r = c * 8 + srow;
        gload_lds16(A + (size_t)(row0 + r) * C_ + scol8 * 8, As[0] + c * 512);
    }
#pragma unroll
    for (int i = 0; i < 2; i++) {
        int c = w * 2 + i;
        int r = c * 8 + srow;
        gload_lds16(Bt + (size_t)(col0 + r) * C_ + scol8 * 8, Bs[0] + c * 512);
    }

#pragma unroll
    for (int kt = 0; kt < 8; kt++) {
        int cur = kt & 1;
        if (kt < 7) {
            int k0 = (kt + 1) * 64;
#pragma unroll
            for (int i = 0; i < 4; i++) {
                int c = w * 4 + i;
                int r = c * 8 + srow;
                gload_lds16(A + (size_t)(row0 + r) * C_ + k0 + scol8 * 8,
                            As[cur ^ 1] + c * 512);
            }
#pragma unroll
            for (int i = 0; i < 2; i++) {
                int c = w * 2 + i;
                int r = c * 8 + srow;
                gload_lds16(Bt + (size_t)(col0 + r) * C_ + k0 + scol8 * 8,
                            Bs[cur ^ 1] + c * 512);
            }
            wait_vmcnt<6>();
        } else {
            wait_vmcnt<0>();
        }
        barrier_raw();
        const ushort* Ac = As[cur];
        const ushort* Bc = Bs[cur];
        __builtin_amdgcn_s_setprio(1);
#pragma unroll
        for (int s = 0; s < 2; s++) {
            short8 a[4], b[2];
            int cs = ((4 * s + g) ^ (ql & 7)) * 8;
#pragma unroll
            for (int mt = 0; mt < 4; mt++)
                a[mt] = *(const short8*)(Ac + (wm + mt * 16 + ql) * 64 + cs);
#pragma unroll
            for (int nt = 0; nt < 2; nt++)
                b[nt] = *(const short8*)(Bc + (wn + nt * 16 + ql) * 64 + cs);
#pragma unroll
            for (int mt = 0; mt < 4; mt++)
#pragma unroll
                for (int nt = 0; nt < 2; nt++)
                    acc[mt][nt] = __builtin_amdgcn_mfma_f32_16x16x32_bf16(
                        a[mt], b[nt], acc[mt][nt], 0, 0, 0);
        }
        __builtin_amdgcn_s_setprio(0);
        barrier_raw();
    }
}

// ---------------- K1: QKV projection, 128x64 tiles, LDS-bounce epilogue ----------------
// grid 1536, XCD-chunked (per XCD: A-slab 1MB + B 1.5MB < 4MB L2). 3 blocks/CU.
__global__ __launch_bounds__(256) void k_qkv(const ushort* __restrict__ xt,
                                             const ushort* __restrict__ Wqkvt,
                                             const float* __restrict__ bq,
                                             const float* __restrict__ bk,
                                             const float* __restrict__ bv,
                                             ushort* __restrict__ Qh,
                                             ushort* __restrict__ Kh,
                                             ushort* __restrict__ Vt) {
    __shared__ __align__(16) ushort As[2][8192];
    __shared__ __align__(16) ushort Bs[2][4096];
    f32x4 acc[4][2];
    int tid = threadIdx.x;
    int L = blockIdx.x;                    // 1536 blocks
    int n = L >> 3, xcd = L & 7;           // n in [0,192)
    int row0 = (xcd * 8 + (n & 7)) * 128;  // 64 row-blocks
    int col0 = (n >> 3) * 64;              // 24 col-blocks
    gemm_core64(xt, Wqkvt, row0, col0, tid, As, Bs, acc);
    int lane = tid & 63, w = tid >> 6;
    int ql = lane & 15, g = lane >> 4;
    int wm = (w >> 1) * 64, wn = (w & 1) * 32;
    int which = col0 >> 9;  // 0=Q 1=K 2=V (block entirely within one segment)
    const float* bias = (which == 0) ? bq : (which == 1) ? bk : bv;
    float bscale = (which == 0) ? QSCALE : 1.0f;
    ushort* Lt = &As[0][0];  // 16KB bounce tile (gemm LDS dead after final barrier)

    if (which != 2) {
        // Q/K: Lt[t(128)][c(64)] with granule swizzle, then coalesced row stores
        ushort* dst = (which == 0) ? Qh : Kh;
#pragma unroll
        for (int mt = 0; mt < 4; mt++)
#pragma unroll
            for (int nt = 0; nt < 2; nt++) {
                int col = wn + nt * 16 + ql;
                float bsv = bias[(col0 + col) & 511] * bscale;
#pragma unroll
                for (int r = 0; r < 4; r++) {
                    int row = wm + mt * 16 + 4 * g + r;
                    int sw = col ^ ((row & 7) << 3);
                    Lt[row * 64 + sw] = f2bf(acc[mt][nt][r] + bsv);
                }
            }
        __syncthreads();
#pragma unroll
        for (int i = 0; i < 4; i++) {
            int task = i * 256 + tid;
            int row = task >> 3, gran = task & 7;
            int sg = gran ^ (row & 7);
            short8 vle = *(const short8*)(Lt + row * 64 + sg * 8);
            int gcol = col0 + gran * 8;
            int hc = gcol & 511, h = hc >> 6, d = hc & 63;
            int grow = row0 + row, b = grow >> 10, t = grow & 1023;
            *(short8*)(dst + ((size_t)(b * NH_ + h) * T_ + t) * HD_ + d) = vle;
        }
    } else {
        // V: Lt[d(64)][t(128)] with 4-t-granule swizzle, coalesced t-row stores
#pragma unroll
        for (int mt = 0; mt < 4; mt++)
#pragma unroll
            for (int nt = 0; nt < 2; nt++) {
                int col = wn + nt * 16 + ql;
                float bsv = bias[(col0 + col) & 511] * bscale;
                int rowb = wm + mt * 16 + 4 * g;
                int swz = (rowb >> 2) ^ (col & 31);
                us4 pk;
#pragma unroll
                for (int r = 0; r < 4; r++) pk[r] = f2bf(acc[mt][nt][r] + bsv);
                *(us4*)(Lt + col * 128 + swz * 4) = pk;
            }
        __syncthreads();
#pragma unroll
        for (int i = 0; i < 4; i++) {
            int task = i * 256 + tid;
            int colr = task >> 4, gran = task & 15;
            int g4a = (2 * gran) ^ (colr & 31);
            int g4b = (2 * gran + 1) ^ (colr & 31);
            us4 lo = *(const us4*)(Lt + colr * 128 + g4a * 4);
            us4 hi4 = *(const us4*)(Lt + colr * 128 + g4b * 4);
            us4 arr[2] = {lo, hi4};
            short8 vle;
            __builtin_memcpy(&vle, arr, 16);
            int hc = (col0 + colr) & 511, h = hc >> 6, d = hc & 63;
            int grow = row0 + gran * 8, b = grow >> 10, t = grow & 1023;
            *(short8*)(Vt + ((size_t)(b * NH_ + h) * HD_ + d) * T_ + t) = vle;
        }
    }
}

// ---------------- K2: flash attention (R16/R19 verified structure) ----------------
__global__ __launch_bounds__(256) void k_attn(const ushort* __restrict__ Qh,
                                              const ushort* __restrict__ Kh,
                                              const ushort* __restrict__ Vt,
                                              ushort* __restrict__ Y) {
    __shared__ __align__(16) ushort KV[8][4096];  // K slots 0-3, V slots 4-7
    int tid = threadIdx.x, lane = tid & 63, w = tid >> 6;
    int hi = lane >> 5, l31 = lane & 31, l7 = lane & 7;
    int bh = blockIdx.x & 63, q0 = (blockIdx.x >> 6) * 128;
    int b = bh >> 3, h = bh & 7;
    int srow = lane >> 3;
    int scol8 = l7 ^ (srow & 7);
    const ushort* Kbase = Kh + (size_t)bh * T_ * HD_;
    const ushort* Vbase = Vt + (size_t)bh * HD_ * T_;
    const ushort* kv = &KV[0][0];

    short8 qa[4];
#pragma unroll
    for (int s = 0; s < 4; s++)
        qa[s] = *(const short8*)(Qh + ((size_t)bh * T_ + q0 + w * 32 + l31) * HD_ +
                                 s * 16 + hi * 8);

    int fofs[4];
#pragma unroll
    for (int s = 0; s < 4; s++) fofs[s] = ((2 * s + hi) ^ l7) * 8;
    int rowlo = l31 * 64;

    short8 ones;
    {
        short ov = (l31 == 0) ? (short)0x3F80 : (short)0;
#pragma unroll
        for (int j = 0; j < 8; j++) ones[j] = ov;
    }

    f32x16 o0, o1, o5, z16;
#pragma unroll
    for (int i = 0; i < 16; i++) { o0[i] = 0.f; o1[i] = 0.f; o5[i] = 0.f; z16[i] = 0.f; }

    // parity-banked packed-P from previous tile (compile-time indexed)
    unsigned pk0[2][8], pk1[2][8];

#define PV_BLOCK(P0, P1, VSL)                                                   \
    __builtin_amdgcn_s_setprio(1);                                              \
    _Pragma("unroll")                                                           \
    for (int t4 = 0; t4 < 4; t4++) {                                            \
        const int h2 = t4 & 1;                                                  \
        unsigned c0, c1, c2v, c3v;                                              \
        if (t4 < 2) { c0 = (P0)[4 * h2 + 0]; c2v = (P0)[4 * h2 + 2];            \
                      c1 = (P0)[4 * h2 + 1]; c3v = (P0)[4 * h2 + 3]; }          \
        else        { c0 = (P1)[4 * h2 + 0]; c2v = (P1)[4 * h2 + 2];            \
                      c1 = (P1)[4 * h2 + 1]; c3v = (P1)[4 * h2 + 3]; }          \
        asm("v_permlane32_swap_b32 %0, %1" : "+v"(c0), "+v"(c2v));              \
        asm("v_permlane32_swap_b32 %0, %1" : "+v"(c1), "+v"(c3v));              \
        unsigned au[4] = {c0, c1, c2v, c3v};                                    \
        short8 pa;                                                              \
        __builtin_memcpy(&pa, au, 16);                                          \
        short8 vb0 = *(const short8*)(kv + (4 + (VSL)) * 4096 + rowlo + fofs[t4]);        \
        short8 vb1 = *(const short8*)(kv + (4 + (VSL)) * 4096 + 2048 + rowlo + fofs[t4]); \
        o0 = __builtin_amdgcn_mfma_f32_32x32x16_bf16(pa, vb0, o0, 0, 0, 0);     \
        o1 = __builtin_amdgcn_mfma_f32_32x32x16_bf16(pa, vb1, o1, 0, 0, 0);     \
        o5 = __builtin_amdgcn_mfma_f32_32x32x16_bf16(pa, ones, o5, 0, 0, 0);    \
    }                                                                           \
    __builtin_amdgcn_s_setprio(0);

    // prologue: tiles 0,1 -> slots 0,1
#pragma unroll
    for (int tt = 0; tt < 2; tt++) {
#pragma unroll
        for (int i = 0; i < 2; i++) {
            int c = w * 2 + i;
            int r = c * 8 + srow;
            gload_lds16(Kbase + (size_t)(tt * 64 + r) * HD_ + scol8 * 8,
                        &KV[tt][0] + c * 512);
            gload_lds16(Vbase + (size_t)r * T_ + tt * 64 + scol8 * 8,
                        &KV[4 + tt][0] + c * 512);
        }
    }

#pragma unroll
    for (int t = 0; t < 16; t++) {
        const int sl = t & 3;
        const int par = t & 1;
        if (t < 15) {
            wait_vmcnt<4>();
        } else {
            wait_vmcnt<0>();
        }
        barrier_raw();
        if (t < 14) {
            const int ds = (t + 2) & 3;
            int kv0 = (t + 2) * 64;
#pragma unroll
            for (int i = 0; i < 2; i++) {
                int c = w * 2 + i;
                int r = c * 8 + srow;
                gload_lds16(Kbase + (size_t)(kv0 + r) * HD_ + scol8 * 8,
                            &KV[ds][0] + c * 512);
                gload_lds16(Vbase + (size_t)r * T_ + kv0 + scol8 * 8,
                            &KV[4 + ds][0] + c * 512);
            }
        }

        f32x16 sT0, sT1;
        __builtin_amdgcn_s_setprio(1);
        {
            short8 ka0 = *(const short8*)(kv + sl * 4096 + rowlo + fofs[0]);
            short8 ka1 = *(const short8*)(kv + sl * 4096 + 2048 + rowlo + fofs[0]);
            sT0 = __builtin_amdgcn_mfma_f32_32x32x16_bf16(ka0, qa[0], z16, 0, 0, 0);
            sT1 = __builtin_amdgcn_mfma_f32_32x32x16_bf16(ka1, qa[0], z16, 0, 0, 0);
        }
#pragma unroll
        for (int s = 1; s < 4; s++) {
            short8 ka0 = *(const short8*)(kv + sl * 4096 + rowlo + fofs[s]);
            short8 ka1 = *(const short8*)(kv + sl * 4096 + 2048 + rowlo + fofs[s]);
            sT0 = __builtin_amdgcn_mfma_f32_32x32x16_bf16(ka0, qa[s], sT0, 0, 0, 0);
            sT1 = __builtin_amdgcn_mfma_f32_32x32x16_bf16(ka1, qa[s], sT1, 0, 0, 0);
        }
        __builtin_amdgcn_s_setprio(0);

        if (t == 1 || t == 3 || t == 5 || t == 7 || t == 9 || t == 11 || t == 13 || t == 15) {
            PV_BLOCK(pk0[0], pk1[0], (t - 1) & 3)
        } else if (t > 0) {
            PV_BLOCK(pk0[1], pk1[1], (t - 1) & 3)
        }

#pragma unroll
        for (int i = 0; i < 8; i++) {
            pk0[par][i] = pack2bf(__builtin_amdgcn_exp2f(sT0[2 * i]),
                                  __builtin_amdgcn_exp2f(sT0[2 * i + 1]));
            pk1[par][i] = pack2bf(__builtin_amdgcn_exp2f(sT1[2 * i]),
                                  __builtin_amdgcn_exp2f(sT1[2 * i + 1]));
        }
    }

    PV_BLOCK(pk0[1], pk1[1], 3)
#undef PV_BLOCK

#pragma unroll
    for (int r = 0; r < 16; r++) {
        float li = 1.0f / __shfl(o5[r], hi * 32);
        int qr = (r & 3) + 8 * (r >> 2) + 4 * hi;
        int trow = q0 + w * 32 + qr;
        size_t base = ((size_t)b * T_ + trow) * C_ + h * HD_;
        Y[base + l31] = f2bf(o0[r] * li);
        Y[base + 32 + l31] = f2bf(o1[r] * li);
    }
}

// ---------------- K3: O projection, 128x64 tiles (R20 verified) ----------------
__global__ __launch_bounds__(256) void k_oproj(const ushort* __restrict__ Y,
                                               const ushort* __restrict__ Wot,
                                               const float* __restrict__ bo,
                                               const float* __restrict__ x,
                                               float* __restrict__ out) {
    __shared__ __align__(16) ushort As[2][8192];
    __shared__ __align__(16) ushort Bs[2][4096];
    f32x4 acc[4][2];
    int tid = threadIdx.x;
    int L = blockIdx.x;                    // 512 blocks
    int n = L >> 3, xcd = L & 7;
    int row0 = (xcd * 8 + (n & 7)) * 128;
    int col0 = (n >> 3) * 64;
    gemm_core64(Y, Wot, row0, col0, tid, As, Bs, acc);
    int lane = tid & 63, w = tid >> 6;
    int ql = lane & 15, g = lane >> 4;
    int wm = (w >> 1) * 64, wn = (w & 1) * 32;
#pragma unroll
    for (int mt = 0; mt < 4; mt++) {
        int grow0 = row0 + wm + mt * 16 + (g << 2);
        int b = grow0 >> 10, t = grow0 & 1023;
#pragma unroll
        for (int nt = 0; nt < 2; nt++) {
            int c = col0 + wn + nt * 16 + ql;
            float bsv = bo[c];
            size_t off = ((size_t)b * C_ + c) * T_ + t;
            float4 xv = *(const float4*)(x + off);
            float4 ov;
            ov.x = acc[mt][nt][0] + xv.x + bsv;
            ov.y = acc[mt][nt][1] + xv.y + bsv;
            ov.z = acc[mt][nt][2] + xv.z + bsv;
            ov.w = acc[mt][nt][3] + xv.w + bsv;
            *(float4*)(out + off) = ov;
        }
    }
}

extern "C" void kernel_launch(void* const* d_in, const int* in_sizes, int n_in,
                              void* d_out, int out_size, void* d_ws, size_t ws_size,
                              hipStream_t stream) {
    const float* x  = (const float*)d_in[0];
    const float* Wq = (const float*)d_in[1];
    const float* bq = (const float*)d_in[2];
    const float* Wk = (const float*)d_in[3];
    const float* bk = (const float*)d_in[4];
    const float* Wv = (const float*)d_in[5];
    const float* bv = (const float*)d_in[6];
    const float* Wo = (const float*)d_in[7];
    const float* bo = (const float*)d_in[8];
    float* out = (float*)d_out;

    char* ws = (char*)d_ws;
    ushort* xt    = (ushort*)(ws + 0);          // 8 MB; reused as Y after K1
    ushort* Wqkvt = (ushort*)(ws + 8388608);
    ushort* Wot   = (ushort*)(ws + 9961472);
    ushort* Qh    = (ushort*)(ws + 10485760);
    ushort* Kh    = (ushort*)(ws + 18874368);
    ushort* Vt    = (ushort*)(ws + 27262976);
    ushort* Yw    = xt;

    k_prep<<<dim3(5120), 256, 0, stream>>>(x, Wq, Wk, Wv, Wo, xt, Wqkvt, Wot);
    k_qkv<<<dim3(1536), 256, 0, stream>>>(xt, Wqkvt, bq, bk, bv, Qh, Kh, Vt);
    k_attn<<<dim3(512), 256, 0, stream>>>(Qh, Kh, Vt, Yw);
    k_oproj<<<dim3(512), 256, 0, stream>>>(Yw, Wot, bo, x, out);
}

// Round 22
// 69.622 us; speedup vs baseline: 1.5720x; 1.0053x over previous
//
#include <hip/hip_runtime.h>
#include <hip/hip_bf16.h>

#define B_  8
#define C_  512
#define T_  1024
#define NH_ 8
#define HD_ 64

// exp(S) computed as exp2(S*log2e); log2e folded into Wq/bq scale.
#define QSCALE 0.1803368801111243f   // 0.125 * log2(e)

using short8 = __attribute__((ext_vector_type(8))) short;
using f32x4  = __attribute__((ext_vector_type(4))) float;
using f32x16 = __attribute__((ext_vector_type(16))) float;
using us4    = __attribute__((ext_vector_type(4))) unsigned short;

__device__ __forceinline__ unsigned short f2bf(float f) {
    unsigned u = __builtin_bit_cast(unsigned, f);
    u += 0x7fff + ((u >> 16) & 1);
    return (unsigned short)(u >> 16);
}
__device__ __forceinline__ unsigned pack2bf(float lo, float hi) {
    __hip_bfloat162 h = __float22bfloat162_rn(float2{lo, hi});
    unsigned u;
    __builtin_memcpy(&u, &h, 4);
    return u;
}

// async global->LDS, 16B per lane. LDS dest = wave-uniform base + lane*16.
__device__ __forceinline__ void gload_lds16(const ushort* g, ushort* l) {
    __builtin_amdgcn_global_load_lds(
        (const __attribute__((address_space(1))) void*)g,
        (__attribute__((address_space(3))) void*)l, 16, 0, 0);
}

// counted vmcnt wait + scheduling fence (rule 18)
template <int N>
__device__ __forceinline__ void wait_vmcnt() {
    asm volatile("s_waitcnt vmcnt(%0)" ::"n"(N) : "memory");
    __builtin_amdgcn_sched_barrier(0);
}
__device__ __forceinline__ void barrier_raw() {
    __builtin_amdgcn_sched_barrier(0);
    __builtin_amdgcn_s_barrier();
}

// ---------------- K0: fused prep — x transpose (vectorized) + W transposes ----------------
// x branch: 64c x 64t tiles; float4 coalesced reads, bf16 into LDS [t][72-pad]
// (144B row stride: 16B-aligned rows, <=2-way banks), ds_read_b128 + ushort8 writes.
__global__ __launch_bounds__(256) void k_prep(const float* __restrict__ x,
                                              const float* __restrict__ Wq,
                                              const float* __restrict__ Wk,
                                              const float* __restrict__ Wv,
                                              const float* __restrict__ Wo,
                                              ushort* __restrict__ xt,
                                              ushort* __restrict__ Wqkvt,
                                              ushort* __restrict__ Wot) {
    int L = blockIdx.x;
    if (L < 1024) {
        __shared__ __align__(16) ushort tile[64 * 72];
        int b = L >> 7, rem = L & 127;            // 8 b x (8 cblk x 16 tblk)
        int c0 = (rem >> 4) * 64, t0 = (rem & 15) * 64;
#pragma unroll
        for (int k = 0; k < 4; k++) {
            int task = threadIdx.x + k * 256;
            int cl = task >> 4, t4 = task & 15;
            float4 v = *(const float4*)(x + ((size_t)b * C_ + c0 + cl) * T_ + t0 + t4 * 4);
            tile[(t4 * 4 + 0) * 72 + cl] = f2bf(v.x);
            tile[(t4 * 4 + 1) * 72 + cl] = f2bf(v.y);
            tile[(t4 * 4 + 2) * 72 + cl] = f2bf(v.z);
            tile[(t4 * 4 + 3) * 72 + cl] = f2bf(v.w);
        }
        __syncthreads();
#pragma unroll
        for (int p = 0; p < 2; p++) {
            int task = threadIdx.x + p * 256;
            int tr = task >> 3, cg = task & 7;
            short8 vle = *(const short8*)(&tile[tr * 72 + cg * 8]);
            *(short8*)(xt + ((size_t)b * T_ + t0 + tr) * C_ + c0 + cg * 8) = vle;
        }
    } else {
        __shared__ float wtile[32][33];
        int LL = L - 1024;
        int m = LL >> 8, rem = LL & 255;
        int k0 = (rem & 15) * 32, n0 = (rem >> 4) * 32;
        const float* W = (m == 0) ? Wq : (m == 1) ? Wk : (m == 2) ? Wv : Wo;
        ushort* dst = (m < 3) ? (Wqkvt + (size_t)m * C_ * C_) : Wot;
        float scale = (m == 0) ? QSCALE : 1.0f;
        int tx = threadIdx.x & 31, ty = threadIdx.x >> 5;
#pragma unroll
        for (int i = 0; i < 4; i++)
            wtile[ty + i * 8][tx] = W[(size_t)(k0 + ty + i * 8) * C_ + n0 + tx];
        __syncthreads();
#pragma unroll
        for (int i = 0; i < 4; i++)
            dst[(size_t)(n0 + ty + i * 8) * C_ + k0 + tx] = f2bf(wtile[tx][ty + i * 8] * scale);
    }
}

// ---------------- shared 128x64-tile GEMM core ----------------
// A-tile 128x64 (16 chunks), B-tile 64x64 (8 chunks); 6 loads/wave/K-step,
// counted vmcnt(6), double-buffered, 2 barriers/iter. LDS 48KB -> 3 blocks/CU.
__device__ __forceinline__ void gemm_core64(const ushort* __restrict__ A,
                                            const ushort* __restrict__ Bt,
                                            int row0, int col0, int tid,
                                            ushort (*As)[8192], ushort (*Bs)[4096],
                                            f32x4 acc[4][2]) {
    f32x4 zero = {0.f, 0.f, 0.f, 0.f};
#pragma unroll
    for (int i = 0; i < 4; i++)
#pragma unroll
        for (int j = 0; j < 2; j++) acc[i][j] = zero;
    int lane = tid & 63, w = tid >> 6;
    int ql = lane & 15, g = lane >> 4;
    int wm = (w >> 1) * 64, wn = (w & 1) * 32;
    int srow = lane >> 3;
    int scol8 = (lane & 7) ^ (srow & 7);

#pragma unroll
    for (int i = 0; i < 4; i++) {
        int c = w * 4 + i;
        int r = c * 8 + srow;
        gload_lds16(A + (size_t)(row0 + r) * C_ + scol8 * 8, As[0] + c * 512);
    }
#pragma unroll
    for (int i = 0; i < 2; i++) {
        int c = w * 2 + i;
        int r = c * 8 + srow;
        gload_lds16(Bt + (size_t)(col0 + r) * C_ + scol8 * 8, Bs[0] + c * 512);
    }

#pragma unroll
    for (int kt = 0; kt < 8; kt++) {
        int cur = kt & 1;
        if (kt < 7) {
            int k0 = (kt + 1) * 64;
#pragma unroll
            for (int i = 0; i < 4; i++) {
                int c = w * 4 + i;
                int r = c * 8 + srow;
                gload_lds16(A + (size_t)(row0 + r) * C_ + k0 + scol8 * 8,
                            As[cur ^ 1] + c * 512);
            }
#pragma unroll
            for (int i = 0; i < 2; i++) {
                int c = w * 2 + i;
                int r = c * 8 + srow;
                gload_lds16(Bt + (size_t)(col0 + r) * C_ + k0 + scol8 * 8,
                            Bs[cur ^ 1] + c * 512);
            }
            wait_vmcnt<6>();
        } else {
            wait_vmcnt<0>();
        }
        barrier_raw();
        const ushort* Ac = As[cur];
        const ushort* Bc = Bs[cur];
        __builtin_amdgcn_s_setprio(1);
#pragma unroll
        for (int s = 0; s < 2; s++) {
            short8 a[4], b[2];
            int cs = ((4 * s + g) ^ (ql & 7)) * 8;
#pragma unroll
            for (int mt = 0; mt < 4; mt++)
                a[mt] = *(const short8*)(Ac + (wm + mt * 16 + ql) * 64 + cs);
#pragma unroll
            for (int nt = 0; nt < 2; nt++)
                b[nt] = *(const short8*)(Bc + (wn + nt * 16 + ql) * 64 + cs);
#pragma unroll
            for (int mt = 0; mt < 4; mt++)
#pragma unroll
                for (int nt = 0; nt < 2; nt++)
                    acc[mt][nt] = __builtin_amdgcn_mfma_f32_16x16x32_bf16(
                        a[mt], b[nt], acc[mt][nt], 0, 0, 0);
        }
        __builtin_amdgcn_s_setprio(0);
        barrier_raw();
    }
}

// ---------------- K1: QKV projection, 128x64 tiles, LDS-bounce epilogue ----------------
__global__ __launch_bounds__(256) void k_qkv(const ushort* __restrict__ xt,
                                             const ushort* __restrict__ Wqkvt,
                                             const float* __restrict__ bq,
                                             const float* __restrict__ bk,
                                             const float* __restrict__ bv,
                                             ushort* __restrict__ Qh,
                                             ushort* __restrict__ Kh,
                                             ushort* __restrict__ Vt) {
    __shared__ __align__(16) ushort As[2][8192];
    __shared__ __align__(16) ushort Bs[2][4096];
    f32x4 acc[4][2];
    int tid = threadIdx.x;
    int L = blockIdx.x;                    // 1536 blocks
    int n = L >> 3, xcd = L & 7;           // n in [0,192)
    int row0 = (xcd * 8 + (n & 7)) * 128;  // 64 row-blocks
    int col0 = (n >> 3) * 64;              // 24 col-blocks
    gemm_core64(xt, Wqkvt, row0, col0, tid, As, Bs, acc);
    int lane = tid & 63, w = tid >> 6;
    int ql = lane & 15, g = lane >> 4;
    int wm = (w >> 1) * 64, wn = (w & 1) * 32;
    int which = col0 >> 9;  // 0=Q 1=K 2=V
    const float* bias = (which == 0) ? bq : (which == 1) ? bk : bv;
    float bscale = (which == 0) ? QSCALE : 1.0f;
    ushort* Lt = &As[0][0];  // 16KB bounce tile

    if (which != 2) {
        ushort* dst = (which == 0) ? Qh : Kh;
#pragma unroll
        for (int mt = 0; mt < 4; mt++)
#pragma unroll
            for (int nt = 0; nt < 2; nt++) {
                int col = wn + nt * 16 + ql;
                float bsv = bias[(col0 + col) & 511] * bscale;
#pragma unroll
                for (int r = 0; r < 4; r++) {
                    int row = wm + mt * 16 + 4 * g + r;
                    int sw = col ^ ((row & 7) << 3);
                    Lt[row * 64 + sw] = f2bf(acc[mt][nt][r] + bsv);
                }
            }
        __syncthreads();
#pragma unroll
        for (int i = 0; i < 4; i++) {
            int task = i * 256 + tid;
            int row = task >> 3, gran = task & 7;
            int sg = gran ^ (row & 7);
            short8 vle = *(const short8*)(Lt + row * 64 + sg * 8);
            int gcol = col0 + gran * 8;
            int hc = gcol & 511, h = hc >> 6, d = hc & 63;
            int grow = row0 + row, b = grow >> 10, t = grow & 1023;
            *(short8*)(dst + ((size_t)(b * NH_ + h) * T_ + t) * HD_ + d) = vle;
        }
    } else {
#pragma unroll
        for (int mt = 0; mt < 4; mt++)
#pragma unroll
            for (int nt = 0; nt < 2; nt++) {
                int col = wn + nt * 16 + ql;
                float bsv = bias[(col0 + col) & 511] * bscale;
                int rowb = wm + mt * 16 + 4 * g;
                int swz = (rowb >> 2) ^ (col & 31);
                us4 pk;
#pragma unroll
                for (int r = 0; r < 4; r++) pk[r] = f2bf(acc[mt][nt][r] + bsv);
                *(us4*)(Lt + col * 128 + swz * 4) = pk;
            }
        __syncthreads();
#pragma unroll
        for (int i = 0; i < 4; i++) {
            int task = i * 256 + tid;
            int colr = task >> 4, gran = task & 15;
            int g4a = (2 * gran) ^ (colr & 31);
            int g4b = (2 * gran + 1) ^ (colr & 31);
            us4 lo = *(const us4*)(Lt + colr * 128 + g4a * 4);
            us4 hi4 = *(const us4*)(Lt + colr * 128 + g4b * 4);
            us4 arr[2] = {lo, hi4};
            short8 vle;
            __builtin_memcpy(&vle, arr, 16);
            int hc = (col0 + colr) & 511, h = hc >> 6, d = hc & 63;
            int grow = row0 + gran * 8, b = grow >> 10, t = grow & 1023;
            *(short8*)(Vt + ((size_t)(b * NH_ + h) * HD_ + d) * T_ + t) = vle;
        }
    }
}

// ---------------- K2: flash attention (R16/R19 verified structure) ----------------
__global__ __launch_bounds__(256) void k_attn(const ushort* __restrict__ Qh,
                                              const ushort* __restrict__ Kh,
                                              const ushort* __restrict__ Vt,
                                              ushort* __restrict__ Y) {
    __shared__ __align__(16) ushort KV[8][4096];  // K slots 0-3, V slots 4-7
    int tid = threadIdx.x, lane = tid & 63, w = tid >> 6;
    int hi = lane >> 5, l31 = lane & 31, l7 = lane & 7;
    int bh = blockIdx.x & 63, q0 = (blockIdx.x >> 6) * 128;
    int b = bh >> 3, h = bh & 7;
    int srow = lane >> 3;
    int scol8 = l7 ^ (srow & 7);
    const ushort* Kbase = Kh + (size_t)bh * T_ * HD_;
    const ushort* Vbase = Vt + (size_t)bh * HD_ * T_;
    const ushort* kv = &KV[0][0];

    short8 qa[4];
#pragma unroll
    for (int s = 0; s < 4; s++)
        qa[s] = *(const short8*)(Qh + ((size_t)bh * T_ + q0 + w * 32 + l31) * HD_ +
                                 s * 16 + hi * 8);

    int fofs[4];
#pragma unroll
    for (int s = 0; s < 4; s++) fofs[s] = ((2 * s + hi) ^ l7) * 8;
    int rowlo = l31 * 64;

    short8 ones;
    {
        short ov = (l31 == 0) ? (short)0x3F80 : (short)0;
#pragma unroll
        for (int j = 0; j < 8; j++) ones[j] = ov;
    }

    f32x16 o0, o1, o5, z16;
#pragma unroll
    for (int i = 0; i < 16; i++) { o0[i] = 0.f; o1[i] = 0.f; o5[i] = 0.f; z16[i] = 0.f; }

    // parity-banked packed-P from previous tile (compile-time indexed)
    unsigned pk0[2][8], pk1[2][8];

#define PV_BLOCK(P0, P1, VSL)                                                   \
    __builtin_amdgcn_s_setprio(1);                                              \
    _Pragma("unroll")                                                           \
    for (int t4 = 0; t4 < 4; t4++) {                                            \
        const int h2 = t4 & 1;                                                  \
        unsigned c0, c1, c2v, c3v;                                              \
        if (t4 < 2) { c0 = (P0)[4 * h2 + 0]; c2v = (P0)[4 * h2 + 2];            \
                      c1 = (P0)[4 * h2 + 1]; c3v = (P0)[4 * h2 + 3]; }          \
        else        { c0 = (P1)[4 * h2 + 0]; c2v = (P1)[4 * h2 + 2];            \
                      c1 = (P1)[4 * h2 + 1]; c3v = (P1)[4 * h2 + 3]; }          \
        asm("v_permlane32_swap_b32 %0, %1" : "+v"(c0), "+v"(c2v));              \
        asm("v_permlane32_swap_b32 %0, %1" : "+v"(c1), "+v"(c3v));              \
        unsigned au[4] = {c0, c1, c2v, c3v};                                    \
        short8 pa;                                                              \
        __builtin_memcpy(&pa, au, 16);                                          \
        short8 vb0 = *(const short8*)(kv + (4 + (VSL)) * 4096 + rowlo + fofs[t4]);        \
        short8 vb1 = *(const short8*)(kv + (4 + (VSL)) * 4096 + 2048 + rowlo + fofs[t4]); \
        o0 = __builtin_amdgcn_mfma_f32_32x32x16_bf16(pa, vb0, o0, 0, 0, 0);     \
        o1 = __builtin_amdgcn_mfma_f32_32x32x16_bf16(pa, vb1, o1, 0, 0, 0);     \
        o5 = __builtin_amdgcn_mfma_f32_32x32x16_bf16(pa, ones, o5, 0, 0, 0);    \
    }                                                                           \
    __builtin_amdgcn_s_setprio(0);

    // prologue: tiles 0,1 -> slots 0,1
#pragma unroll
    for (int tt = 0; tt < 2; tt++) {
#pragma unroll
        for (int i = 0; i < 2; i++) {
            int c = w * 2 + i;
            int r = c * 8 + srow;
            gload_lds16(Kbase + (size_t)(tt * 64 + r) * HD_ + scol8 * 8,
                        &KV[tt][0] + c * 512);
            gload_lds16(Vbase + (size_t)r * T_ + tt * 64 + scol8 * 8,
                        &KV[4 + tt][0] + c * 512);
        }
    }

#pragma unroll
    for (int t = 0; t < 16; t++) {
        const int sl = t & 3;
        const int par = t & 1;
        if (t < 15) {
            wait_vmcnt<4>();
        } else {
            wait_vmcnt<0>();
        }
        barrier_raw();
        if (t < 14) {
            const int ds = (t + 2) & 3;
            int kv0 = (t + 2) * 64;
#pragma unroll
            for (int i = 0; i < 2; i++) {
                int c = w * 2 + i;
                int r = c * 8 + srow;
                gload_lds16(Kbase + (size_t)(kv0 + r) * HD_ + scol8 * 8,
                            &KV[ds][0] + c * 512);
                gload_lds16(Vbase + (size_t)r * T_ + kv0 + scol8 * 8,
                            &KV[4 + ds][0] + c * 512);
            }
        }

        f32x16 sT0, sT1;
        __builtin_amdgcn_s_setprio(1);
        {
            short8 ka0 = *(const short8*)(kv + sl * 4096 + rowlo + fofs[0]);
            short8 ka1 = *(const short8*)(kv + sl * 4096 + 2048 + rowlo + fofs[0]);
            sT0 = __builtin_amdgcn_mfma_f32_32x32x16_bf16(ka0, qa[0], z16, 0, 0, 0);
            sT1 = __builtin_amdgcn_mfma_f32_32x32x16_bf16(ka1, qa[0], z16, 0, 0, 0);
        }
#pragma unroll
        for (int s = 1; s < 4; s++) {
            short8 ka0 = *(const short8*)(kv + sl * 4096 + rowlo + fofs[s]);
            short8 ka1 = *(const short8*)(kv + sl * 4096 + 2048 + rowlo + fofs[s]);
            sT0 = __builtin_amdgcn_mfma_f32_32x32x16_bf16(ka0, qa[s], sT0, 0, 0, 0);
            sT1 = __builtin_amdgcn_mfma_f32_32x32x16_bf16(ka1, qa[s], sT1, 0, 0, 0);
        }
        __builtin_amdgcn_s_setprio(0);

        if (t == 1 || t == 3 || t == 5 || t == 7 || t == 9 || t == 11 || t == 13 || t == 15) {
            PV_BLOCK(pk0[0], pk1[0], (t - 1) & 3)
        } else if (t > 0) {
            PV_BLOCK(pk0[1], pk1[1], (t - 1) & 3)
        }

#pragma unroll
        for (int i = 0; i < 8; i++) {
            pk0[par][i] = pack2bf(__builtin_amdgcn_exp2f(sT0[2 * i]),
                                  __builtin_amdgcn_exp2f(sT0[2 * i + 1]));
            pk1[par][i] = pack2bf(__builtin_amdgcn_exp2f(sT1[2 * i]),
                                  __builtin_amdgcn_exp2f(sT1[2 * i + 1]));
        }
    }

    PV_BLOCK(pk0[1], pk1[1], 3)
#undef PV_BLOCK

#pragma unroll
    for (int r = 0; r < 16; r++) {
        float li = 1.0f / __shfl(o5[r], hi * 32);
        int qr = (r & 3) + 8 * (r >> 2) + 4 * hi;
        int trow = q0 + w * 32 + qr;
        size_t base = ((size_t)b * T_ + trow) * C_ + h * HD_;
        Y[base + l31] = f2bf(o0[r] * li);
        Y[base + 32 + l31] = f2bf(o1[r] * li);
    }
}

// ---------------- K3: O projection, 128x64 tiles (R20 verified) ----------------
__global__ __launch_bounds__(256) void k_oproj(const ushort* __restrict__ Y,
                                               const ushort* __restrict__ Wot,
                                               const float* __restrict__ bo,
                                               const float* __restrict__ x,
                                               float* __restrict__ out) {
    __shared__ __align__(16) ushort As[2][8192];
    __shared__ __align__(16) ushort Bs[2][4096];
    f32x4 acc[4][2];
    int tid = threadIdx.x;
    int L = blockIdx.x;                    // 512 blocks
    int n = L >> 3, xcd = L & 7;
    int row0 = (xcd * 8 + (n & 7)) * 128;
    int col0 = (n >> 3) * 64;
    gemm_core64(Y, Wot, row0, col0, tid, As, Bs, acc);
    int lane = tid & 63, w = tid >> 6;
    int ql = lane & 15, g = lane >> 4;
    int wm = (w >> 1) * 64, wn = (w & 1) * 32;
#pragma unroll
    for (int mt = 0; mt < 4; mt++) {
        int grow0 = row0 + wm + mt * 16 + (g << 2);
        int b = grow0 >> 10, t = grow0 & 1023;
#pragma unroll
        for (int nt = 0; nt < 2; nt++) {
            int c = col0 + wn + nt * 16 + ql;
            float bsv = bo[c];
            size_t off = ((size_t)b * C_ + c) * T_ + t;
            float4 xv = *(const float4*)(x + off);
            float4 ov;
            ov.x = acc[mt][nt][0] + xv.x + bsv;
            ov.y = acc[mt][nt][1] + xv.y + bsv;
            ov.z = acc[mt][nt][2] + xv.z + bsv;
            ov.w = acc[mt][nt][3] + xv.w + bsv;
            *(float4*)(out + off) = ov;
        }
    }
}

extern "C" void kernel_launch(void* const* d_in, const int* in_sizes, int n_in,
                              void* d_out, int out_size, void* d_ws, size_t ws_size,
                              hipStream_t stream) {
    const float* x  = (const float*)d_in[0];
    const float* Wq = (const float*)d_in[1];
    const float* bq = (const float*)d_in[2];
    const float* Wk = (const float*)d_in[3];
    const float* bk = (const float*)d_in[4];
    const float* Wv = (const float*)d_in[5];
    const float* bv = (const float*)d_in[6];
    const float* Wo = (const float*)d_in[7];
    const float* bo = (const float*)d_in[8];
    float* out = (float*)d_out;

    char* ws = (char*)d_ws;
    ushort* xt    = (ushort*)(ws + 0);          // 8 MB; reused as Y after K1
    ushort* Wqkvt = (ushort*)(ws + 8388608);
    ushort* Wot   = (ushort*)(ws + 9961472);
    ushort* Qh    = (ushort*)(ws + 10485760);
    ushort* Kh    = (ushort*)(ws + 18874368);
    ushort* Vt    = (ushort*)(ws + 27262976);
    ushort* Yw    = xt;

    k_prep<<<dim3(2048), 256, 0, stream>>>(x, Wq, Wk, Wv, Wo, xt, Wqkvt, Wot);
    k_qkv<<<dim3(1536), 256, 0, stream>>>(xt, Wqkvt, bq, bk, bv, Qh, Kh, Vt);
    k_attn<<<dim3(512), 256, 0, stream>>>(Qh, Kh, Vt, Yw);
    k_oproj<<<dim3(512), 256, 0, stream>>>(Yw, Wot, bo, x, out);
}

// Round 23
// 67.778 us; speedup vs baseline: 1.6148x; 1.0272x over previous
//
#include <hip/hip_runtime.h>
#include <hip/hip_bf16.h>

#define B_  8
#define C_  512
#define T_  1024
#define NH_ 8
#define HD_ 64

// exp(S) computed as exp2(S*log2e); log2e folded into Wq/bq scale.
#define QSCALE 0.1803368801111243f   // 0.125 * log2(e)

using short8 = __attribute__((ext_vector_type(8))) short;
using f32x4  = __attribute__((ext_vector_type(4))) float;
using f32x16 = __attribute__((ext_vector_type(16))) float;
using us4    = __attribute__((ext_vector_type(4))) unsigned short;

__device__ __forceinline__ unsigned short f2bf(float f) {
    unsigned u = __builtin_bit_cast(unsigned, f);
    u += 0x7fff + ((u >> 16) & 1);
    return (unsigned short)(u >> 16);
}
__device__ __forceinline__ unsigned pack2bf(float lo, float hi) {
    __hip_bfloat162 h = __float22bfloat162_rn(float2{lo, hi});
    unsigned u;
    __builtin_memcpy(&u, &h, 4);
    return u;
}

// async global->LDS, 16B per lane. LDS dest = wave-uniform base + lane*16.
__device__ __forceinline__ void gload_lds16(const ushort* g, ushort* l) {
    __builtin_amdgcn_global_load_lds(
        (const __attribute__((address_space(1))) void*)g,
        (__attribute__((address_space(3))) void*)l, 16, 0, 0);
}

// counted vmcnt wait + scheduling fence (rule 18)
template <int N>
__device__ __forceinline__ void wait_vmcnt() {
    asm volatile("s_waitcnt vmcnt(%0)" ::"n"(N) : "memory");
    __builtin_amdgcn_sched_barrier(0);
}
__device__ __forceinline__ void barrier_raw() {
    __builtin_amdgcn_sched_barrier(0);
    __builtin_amdgcn_s_barrier();
}

// ---------------- K0: fused prep — x transpose (vectorized) + W transposes ----------------
__global__ __launch_bounds__(256) void k_prep(const float* __restrict__ x,
                                              const float* __restrict__ Wq,
                                              const float* __restrict__ Wk,
                                              const float* __restrict__ Wv,
                                              const float* __restrict__ Wo,
                                              ushort* __restrict__ xt,
                                              ushort* __restrict__ Wqkvt,
                                              ushort* __restrict__ Wot) {
    int L = blockIdx.x;
    if (L < 1024) {
        __shared__ __align__(16) ushort tile[64 * 72];
        int b = L >> 7, rem = L & 127;
        int c0 = (rem >> 4) * 64, t0 = (rem & 15) * 64;
#pragma unroll
        for (int k = 0; k < 4; k++) {
            int task = threadIdx.x + k * 256;
            int cl = task >> 4, t4 = task & 15;
            float4 v = *(const float4*)(x + ((size_t)b * C_ + c0 + cl) * T_ + t0 + t4 * 4);
            tile[(t4 * 4 + 0) * 72 + cl] = f2bf(v.x);
            tile[(t4 * 4 + 1) * 72 + cl] = f2bf(v.y);
            tile[(t4 * 4 + 2) * 72 + cl] = f2bf(v.z);
            tile[(t4 * 4 + 3) * 72 + cl] = f2bf(v.w);
        }
        __syncthreads();
#pragma unroll
        for (int p = 0; p < 2; p++) {
            int task = threadIdx.x + p * 256;
            int tr = task >> 3, cg = task & 7;
            short8 vle = *(const short8*)(&tile[tr * 72 + cg * 8]);
            *(short8*)(xt + ((size_t)b * T_ + t0 + tr) * C_ + c0 + cg * 8) = vle;
        }
    } else {
        __shared__ float wtile[32][33];
        int LL = L - 1024;
        int m = LL >> 8, rem = LL & 255;
        int k0 = (rem & 15) * 32, n0 = (rem >> 4) * 32;
        const float* W = (m == 0) ? Wq : (m == 1) ? Wk : (m == 2) ? Wv : Wo;
        ushort* dst = (m < 3) ? (Wqkvt + (size_t)m * C_ * C_) : Wot;
        float scale = (m == 0) ? QSCALE : 1.0f;
        int tx = threadIdx.x & 31, ty = threadIdx.x >> 5;
#pragma unroll
        for (int i = 0; i < 4; i++)
            wtile[ty + i * 8][tx] = W[(size_t)(k0 + ty + i * 8) * C_ + n0 + tx];
        __syncthreads();
#pragma unroll
        for (int i = 0; i < 4; i++)
            dst[(size_t)(n0 + ty + i * 8) * C_ + k0 + tx] = f2bf(wtile[tx][ty + i * 8] * scale);
    }
}

// ---------------- shared 128x64-tile GEMM core ----------------
__device__ __forceinline__ void gemm_core64(const ushort* __restrict__ A,
                                            const ushort* __restrict__ Bt,
                                            int row0, int col0, int tid,
                                            ushort (*As)[8192], ushort (*Bs)[4096],
                                            f32x4 acc[4][2]) {
    f32x4 zero = {0.f, 0.f, 0.f, 0.f};
#pragma unroll
    for (int i = 0; i < 4; i++)
#pragma unroll
        for (int j = 0; j < 2; j++) acc[i][j] = zero;
    int lane = tid & 63, w = tid >> 6;
    int ql = lane & 15, g = lane >> 4;
    int wm = (w >> 1) * 64, wn = (w & 1) * 32;
    int srow = lane >> 3;
    int scol8 = (lane & 7) ^ (srow & 7);

#pragma unroll
    for (int i = 0; i < 4; i++) {
        int c = w * 4 + i;
        int r = c * 8 + srow;
        gload_lds16(A + (size_t)(row0 + r) * C_ + scol8 * 8, As[0] + c * 512);
    }
#pragma unroll
    for (int i = 0; i < 2; i++) {
        int c = w * 2 + i;
        int r = c * 8 + srow;
        gload_lds16(Bt + (size_t)(col0 + r) * C_ + scol8 * 8, Bs[0] + c * 512);
    }

#pragma unroll
    for (int kt = 0; kt < 8; kt++) {
        int cur = kt & 1;
        if (kt < 7) {
            int k0 = (kt + 1) * 64;
#pragma unroll
            for (int i = 0; i < 4; i++) {
                int c = w * 4 + i;
                int r = c * 8 + srow;
                gload_lds16(A + (size_t)(row0 + r) * C_ + k0 + scol8 * 8,
                            As[cur ^ 1] + c * 512);
            }
#pragma unroll
            for (int i = 0; i < 2; i++) {
                int c = w * 2 + i;
                int r = c * 8 + srow;
                gload_lds16(Bt + (size_t)(col0 + r) * C_ + k0 + scol8 * 8,
                            Bs[cur ^ 1] + c * 512);
            }
            wait_vmcnt<6>();
        } else {
            wait_vmcnt<0>();
        }
        barrier_raw();
        const ushort* Ac = As[cur];
        const ushort* Bc = Bs[cur];
        __builtin_amdgcn_s_setprio(1);
#pragma unroll
        for (int s = 0; s < 2; s++) {
            short8 a[4], b[2];
            int cs = ((4 * s + g) ^ (ql & 7)) * 8;
#pragma unroll
            for (int mt = 0; mt < 4; mt++)
                a[mt] = *(const short8*)(Ac + (wm + mt * 16 + ql) * 64 + cs);
#pragma unroll
            for (int nt = 0; nt < 2; nt++)
                b[nt] = *(const short8*)(Bc + (wn + nt * 16 + ql) * 64 + cs);
#pragma unroll
            for (int mt = 0; mt < 4; mt++)
#pragma unroll
                for (int nt = 0; nt < 2; nt++)
                    acc[mt][nt] = __builtin_amdgcn_mfma_f32_16x16x32_bf16(
                        a[mt], b[nt], acc[mt][nt], 0, 0, 0);
        }
        __builtin_amdgcn_s_setprio(0);
        barrier_raw();
    }
}

// ---------------- K1: QKV projection, 128x64 tiles, LDS-bounce epilogue ----------------
__global__ __launch_bounds__(256) void k_qkv(const ushort* __restrict__ xt,
                                             const ushort* __restrict__ Wqkvt,
                                             const float* __restrict__ bq,
                                             const float* __restrict__ bk,
                                             const float* __restrict__ bv,
                                             ushort* __restrict__ Qh,
                                             ushort* __restrict__ Kh,
                                             ushort* __restrict__ Vt) {
    __shared__ __align__(16) ushort As[2][8192];
    __shared__ __align__(16) ushort Bs[2][4096];
    f32x4 acc[4][2];
    int tid = threadIdx.x;
    int L = blockIdx.x;
    int n = L >> 3, xcd = L & 7;
    int row0 = (xcd * 8 + (n & 7)) * 128;
    int col0 = (n >> 3) * 64;
    gemm_core64(xt, Wqkvt, row0, col0, tid, As, Bs, acc);
    int lane = tid & 63, w = tid >> 6;
    int ql = lane & 15, g = lane >> 4;
    int wm = (w >> 1) * 64, wn = (w & 1) * 32;
    int which = col0 >> 9;  // 0=Q 1=K 2=V
    const float* bias = (which == 0) ? bq : (which == 1) ? bk : bv;
    float bscale = (which == 0) ? QSCALE : 1.0f;
    ushort* Lt = &As[0][0];

    if (which != 2) {
        ushort* dst = (which == 0) ? Qh : Kh;
#pragma unroll
        for (int mt = 0; mt < 4; mt++)
#pragma unroll
            for (int nt = 0; nt < 2; nt++) {
                int col = wn + nt * 16 + ql;
                float bsv = bias[(col0 + col) & 511] * bscale;
#pragma unroll
                for (int r = 0; r < 4; r++) {
                    int row = wm + mt * 16 + 4 * g + r;
                    int sw = col ^ ((row & 7) << 3);
                    Lt[row * 64 + sw] = f2bf(acc[mt][nt][r] + bsv);
                }
            }
        __syncthreads();
#pragma unroll
        for (int i = 0; i < 4; i++) {
            int task = i * 256 + tid;
            int row = task >> 3, gran = task & 7;
            int sg = gran ^ (row & 7);
            short8 vle = *(const short8*)(Lt + row * 64 + sg * 8);
            int gcol = col0 + gran * 8;
            int hc = gcol & 511, h = hc >> 6, d = hc & 63;
            int grow = row0 + row, b = grow >> 10, t = grow & 1023;
            *(short8*)(dst + ((size_t)(b * NH_ + h) * T_ + t) * HD_ + d) = vle;
        }
    } else {
#pragma unroll
        for (int mt = 0; mt < 4; mt++)
#pragma unroll
            for (int nt = 0; nt < 2; nt++) {
                int col = wn + nt * 16 + ql;
                float bsv = bias[(col0 + col) & 511] * bscale;
                int rowb = wm + mt * 16 + 4 * g;
                int swz = (rowb >> 2) ^ (col & 31);
                us4 pk;
#pragma unroll
                for (int r = 0; r < 4; r++) pk[r] = f2bf(acc[mt][nt][r] + bsv);
                *(us4*)(Lt + col * 128 + swz * 4) = pk;
            }
        __syncthreads();
#pragma unroll
        for (int i = 0; i < 4; i++) {
            int task = i * 256 + tid;
            int colr = task >> 4, gran = task & 15;
            int g4a = (2 * gran) ^ (colr & 31);
            int g4b = (2 * gran + 1) ^ (colr & 31);
            us4 lo = *(const us4*)(Lt + colr * 128 + g4a * 4);
            us4 hi4 = *(const us4*)(Lt + colr * 128 + g4b * 4);
            us4 arr[2] = {lo, hi4};
            short8 vle;
            __builtin_memcpy(&vle, arr, 16);
            int hc = (col0 + colr) & 511, h = hc >> 6, d = hc & 63;
            int grow = row0 + gran * 8, b = grow >> 10, t = grow & 1023;
            *(short8*)(Vt + ((size_t)(b * NH_ + h) * HD_ + d) * T_ + t) = vle;
        }
    }
}

// ---------------- K2: flash attention, QBLK=256, 8 waves share staged K/V ----------------
// Per-wave structure identical to R16/R19; staged tile now serves 256 q-rows
// (K/V L2 traffic halved). Wave w stages 1 K-chunk + 1 V-chunk (vmcnt(2)).
// grid 256: bh = L&63 -> XCD = h (head-class L2 locality preserved).
__global__ __launch_bounds__(512, 2) void k_attn(const ushort* __restrict__ Qh,
                                                 const ushort* __restrict__ Kh,
                                                 const ushort* __restrict__ Vt,
                                                 ushort* __restrict__ Y) {
    __shared__ __align__(16) ushort KV[8][4096];  // K slots 0-3, V slots 4-7
    int tid = threadIdx.x, lane = tid & 63, w = tid >> 6;   // w in [0,8)
    int hi = lane >> 5, l31 = lane & 31, l7 = lane & 7;
    int bh = blockIdx.x & 63, q0 = (blockIdx.x >> 6) * 256;
    int b = bh >> 3, h = bh & 7;
    int srow = lane >> 3;
    int scol8 = l7 ^ (srow & 7);
    const ushort* Kbase = Kh + (size_t)bh * T_ * HD_;
    const ushort* Vbase = Vt + (size_t)bh * HD_ * T_;
    const ushort* kv = &KV[0][0];

    short8 qa[4];
#pragma unroll
    for (int s = 0; s < 4; s++)
        qa[s] = *(const short8*)(Qh + ((size_t)bh * T_ + q0 + w * 32 + l31) * HD_ +
                                 s * 16 + hi * 8);

    int fofs[4];
#pragma unroll
    for (int s = 0; s < 4; s++) fofs[s] = ((2 * s + hi) ^ l7) * 8;
    int rowlo = l31 * 64;

    short8 ones;
    {
        short ov = (l31 == 0) ? (short)0x3F80 : (short)0;
#pragma unroll
        for (int j = 0; j < 8; j++) ones[j] = ov;
    }

    f32x16 o0, o1, o5, z16;
#pragma unroll
    for (int i = 0; i < 16; i++) { o0[i] = 0.f; o1[i] = 0.f; o5[i] = 0.f; z16[i] = 0.f; }

    unsigned pk0[2][8], pk1[2][8];

#define PV_BLOCK(P0, P1, VSL)                                                   \
    __builtin_amdgcn_s_setprio(1);                                              \
    _Pragma("unroll")                                                           \
    for (int t4 = 0; t4 < 4; t4++) {                                            \
        const int h2 = t4 & 1;                                                  \
        unsigned c0, c1, c2v, c3v;                                              \
        if (t4 < 2) { c0 = (P0)[4 * h2 + 0]; c2v = (P0)[4 * h2 + 2];            \
                      c1 = (P0)[4 * h2 + 1]; c3v = (P0)[4 * h2 + 3]; }          \
        else        { c0 = (P1)[4 * h2 + 0]; c2v = (P1)[4 * h2 + 2];            \
                      c1 = (P1)[4 * h2 + 1]; c3v = (P1)[4 * h2 + 3]; }          \
        asm("v_permlane32_swap_b32 %0, %1" : "+v"(c0), "+v"(c2v));              \
        asm("v_permlane32_swap_b32 %0, %1" : "+v"(c1), "+v"(c3v));              \
        unsigned au[4] = {c0, c1, c2v, c3v};                                    \
        short8 pa;                                                              \
        __builtin_memcpy(&pa, au, 16);                                          \
        short8 vb0 = *(const short8*)(kv + (4 + (VSL)) * 4096 + rowlo + fofs[t4]);        \
        short8 vb1 = *(const short8*)(kv + (4 + (VSL)) * 4096 + 2048 + rowlo + fofs[t4]); \
        o0 = __builtin_amdgcn_mfma_f32_32x32x16_bf16(pa, vb0, o0, 0, 0, 0);     \
        o1 = __builtin_amdgcn_mfma_f32_32x32x16_bf16(pa, vb1, o1, 0, 0, 0);     \
        o5 = __builtin_amdgcn_mfma_f32_32x32x16_bf16(pa, ones, o5, 0, 0, 0);    \
    }                                                                           \
    __builtin_amdgcn_s_setprio(0);

    // prologue: tiles 0,1 -> slots 0,1 (wave w stages chunk w of K and of V)
#pragma unroll
    for (int tt = 0; tt < 2; tt++) {
        int r = w * 8 + srow;
        gload_lds16(Kbase + (size_t)(tt * 64 + r) * HD_ + scol8 * 8,
                    &KV[tt][0] + w * 512);
        gload_lds16(Vbase + (size_t)r * T_ + tt * 64 + scol8 * 8,
                    &KV[4 + tt][0] + w * 512);
    }

#pragma unroll
    for (int t = 0; t < 16; t++) {
        const int sl = t & 3;
        const int par = t & 1;
        if (t < 15) {
            wait_vmcnt<2>();   // tile t's loads landed; t+1's 2 stay in flight
        } else {
            wait_vmcnt<0>();
        }
        barrier_raw();
        if (t < 14) {
            const int ds = (t + 2) & 3;
            int kv0 = (t + 2) * 64;
            int r = w * 8 + srow;
            gload_lds16(Kbase + (size_t)(kv0 + r) * HD_ + scol8 * 8,
                        &KV[ds][0] + w * 512);
            gload_lds16(Vbase + (size_t)r * T_ + kv0 + scol8 * 8,
                        &KV[4 + ds][0] + w * 512);
        }

        f32x16 sT0, sT1;
        __builtin_amdgcn_s_setprio(1);
        {
            short8 ka0 = *(const short8*)(kv + sl * 4096 + rowlo + fofs[0]);
            short8 ka1 = *(const short8*)(kv + sl * 4096 + 2048 + rowlo + fofs[0]);
            sT0 = __builtin_amdgcn_mfma_f32_32x32x16_bf16(ka0, qa[0], z16, 0, 0, 0);
            sT1 = __builtin_amdgcn_mfma_f32_32x32x16_bf16(ka1, qa[0], z16, 0, 0, 0);
        }
#pragma unroll
        for (int s = 1; s < 4; s++) {
            short8 ka0 = *(const short8*)(kv + sl * 4096 + rowlo + fofs[s]);
            short8 ka1 = *(const short8*)(kv + sl * 4096 + 2048 + rowlo + fofs[s]);
            sT0 = __builtin_amdgcn_mfma_f32_32x32x16_bf16(ka0, qa[s], sT0, 0, 0, 0);
            sT1 = __builtin_amdgcn_mfma_f32_32x32x16_bf16(ka1, qa[s], sT1, 0, 0, 0);
        }
        __builtin_amdgcn_s_setprio(0);

        if (t == 1 || t == 3 || t == 5 || t == 7 || t == 9 || t == 11 || t == 13 || t == 15) {
            PV_BLOCK(pk0[0], pk1[0], (t - 1) & 3)
        } else if (t > 0) {
            PV_BLOCK(pk0[1], pk1[1], (t - 1) & 3)
        }

#pragma unroll
        for (int i = 0; i < 8; i++) {
            pk0[par][i] = pack2bf(__builtin_amdgcn_exp2f(sT0[2 * i]),
                                  __builtin_amdgcn_exp2f(sT0[2 * i + 1]));
            pk1[par][i] = pack2bf(__builtin_amdgcn_exp2f(sT1[2 * i]),
                                  __builtin_amdgcn_exp2f(sT1[2 * i + 1]));
        }
    }

    PV_BLOCK(pk0[1], pk1[1], 3)
#undef PV_BLOCK

#pragma unroll
    for (int r = 0; r < 16; r++) {
        float li = 1.0f / __shfl(o5[r], hi * 32);
        int qr = (r & 3) + 8 * (r >> 2) + 4 * hi;
        int trow = q0 + w * 32 + qr;
        size_t base = ((size_t)b * T_ + trow) * C_ + h * HD_;
        Y[base + l31] = f2bf(o0[r] * li);
        Y[base + 32 + l31] = f2bf(o1[r] * li);
    }
}

// ---------------- K3: O projection, 128x64 tiles (R20 verified) ----------------
__global__ __launch_bounds__(256) void k_oproj(const ushort* __restrict__ Y,
                                               const ushort* __restrict__ Wot,
                                               const float* __restrict__ bo,
                                               const float* __restrict__ x,
                                               float* __restrict__ out) {
    __shared__ __align__(16) ushort As[2][8192];
    __shared__ __align__(16) ushort Bs[2][4096];
    f32x4 acc[4][2];
    int tid = threadIdx.x;
    int L = blockIdx.x;
    int n = L >> 3, xcd = L & 7;
    int row0 = (xcd * 8 + (n & 7)) * 128;
    int col0 = (n >> 3) * 64;
    gemm_core64(Y, Wot, row0, col0, tid, As, Bs, acc);
    int lane = tid & 63, w = tid >> 6;
    int ql = lane & 15, g = lane >> 4;
    int wm = (w >> 1) * 64, wn = (w & 1) * 32;
#pragma unroll
    for (int mt = 0; mt < 4; mt++) {
        int grow0 = row0 + wm + mt * 16 + (g << 2);
        int b = grow0 >> 10, t = grow0 & 1023;
#pragma unroll
        for (int nt = 0; nt < 2; nt++) {
            int c = col0 + wn + nt * 16 + ql;
            float bsv = bo[c];
            size_t off = ((size_t)b * C_ + c) * T_ + t;
            float4 xv = *(const float4*)(x + off);
            float4 ov;
            ov.x = acc[mt][nt][0] + xv.x + bsv;
            ov.y = acc[mt][nt][1] + xv.y + bsv;
            ov.z = acc[mt][nt][2] + xv.z + bsv;
            ov.w = acc[mt][nt][3] + xv.w + bsv;
            *(float4*)(out + off) = ov;
        }
    }
}

extern "C" void kernel_launch(void* const* d_in, const int* in_sizes, int n_in,
                              void* d_out, int out_size, void* d_ws, size_t ws_size,
                              hipStream_t stream) {
    const float* x  = (const float*)d_in[0];
    const float* Wq = (const float*)d_in[1];
    const float* bq = (const float*)d_in[2];
    const float* Wk = (const float*)d_in[3];
    const float* bk = (const float*)d_in[4];
    const float* Wv = (const float*)d_in[5];
    const float* bv = (const float*)d_in[6];
    const float* Wo = (const float*)d_in[7];
    const float* bo = (const float*)d_in[8];
    float* out = (float*)d_out;

    char* ws = (char*)d_ws;
    ushort* xt    = (ushort*)(ws + 0);          // 8 MB; reused as Y after K1
    ushort* Wqkvt = (ushort*)(ws + 8388608);
    ushort* Wot   = (ushort*)(ws + 9961472);
    ushort* Qh    = (ushort*)(ws + 10485760);
    ushort* Kh    = (ushort*)(ws + 18874368);
    ushort* Vt    = (ushort*)(ws + 27262976);
    ushort* Yw    = xt;

    k_prep<<<dim3(2048), 256, 0, stream>>>(x, Wq, Wk, Wv, Wo, xt, Wqkvt, Wot);
    k_qkv<<<dim3(1536), 256, 0, stream>>>(xt, Wqkvt, bq, bk, bv, Qh, Kh, Vt);
    k_attn<<<dim3(256), 512, 0, stream>>>(Qh, Kh, Vt, Yw);
    k_oproj<<<dim3(512), 256, 0, stream>>>(Yw, Wot, bo, x, out);
}